// Round 3
// baseline (867.138 us; speedup 1.0000x reference)
//
#include <hip/hip_runtime.h>
#include <math.h>

// Problem constants: B=16, K=4, T=64, N=128, F=16, H=32, NH=8, GH=32
// Sequences: 12288 = 2048 anchor + 2048 pos + 8192 neg. Graphs: 96 = 16+16+64.

typedef __bf16 bf16x8 __attribute__((ext_vector_type(8)));
typedef float  f32x4  __attribute__((ext_vector_type(4)));

__device__ __forceinline__ float fast_rcp(float x) { return __builtin_amdgcn_rcpf(x); }
__device__ __forceinline__ float sigm(float x)     { return fast_rcp(1.f + __expf(-x)); }
__device__ __forceinline__ float tanh_fast(float x){ return fmaf(2.f, fast_rcp(1.f + __expf(-2.f * x)), -1.f); }

// ---------------------------------------------------------------------------
// LSTM via MFMA (unchanged from R2; passed at absmax 2.4e-4).
// ---------------------------------------------------------------------------
__global__ __launch_bounds__(128) void lstm_mfma_kernel(
    const float* __restrict__ anchor, const float* __restrict__ pos,
    const float* __restrict__ neg, const float* __restrict__ Wih,
    const float* __restrict__ Whh, const float* __restrict__ bias,
    float* __restrict__ hn)
{
    __shared__ unsigned int Hbuf[2][16 * 32];   // [dbuf][m][j] packed bf16 hi|lo
    const int tid  = threadIdx.x;
    const int lane = tid & 63;
    const int wid  = tid >> 6;         // 0/1: which j-half this wave owns
    const int l15  = lane & 15;
    const int g4   = lane >> 4;

    for (int i = tid; i < 2 * 16 * 32; i += 128) ((unsigned int*)Hbuf)[i] = 0u;

    bf16x8 whh_hi[4], whh_lo[4], wih_hi[4], wih_lo[4];
    f32x4 bvec[4];
    #pragma unroll
    for (int q = 0; q < 4; ++q) {
        const int c = q * 32 + wid * 16 + l15;   // output col = gate q, unit j
        const float bq = bias[c];
        bvec[q][0] = bq; bvec[q][1] = bq; bvec[q][2] = bq; bvec[q][3] = bq;
        const float* wr = Whh + c * 32 + g4 * 8; // B[k][c] = Whh[c][k], k=8*g4+i
        #pragma unroll
        for (int i = 0; i < 8; ++i) {
            float w = wr[i];
            __bf16 hi = (__bf16)w;
            whh_hi[q][i] = hi;
            whh_lo[q][i] = (__bf16)(w - (float)hi);
        }
        if (g4 < 2) {
            const float* wr2 = Wih + c * 16 + g4 * 8;
            #pragma unroll
            for (int i = 0; i < 8; ++i) {
                float w = wr2[i];
                __bf16 hi = (__bf16)w;
                wih_hi[q][i] = hi;
                wih_lo[q][i] = (__bf16)(w - (float)hi);
            }
        } else {
            #pragma unroll
            for (int i = 0; i < 8; ++i) {
                wih_hi[q][i] = (__bf16)0.f; wih_lo[q][i] = (__bf16)0.f;
            }
        }
    }

    const int s = blockIdx.x * 16 + l15;
    const float* xbase; int sl;
    if (s < 2048)      { xbase = anchor; sl = s; }
    else if (s < 4096) { xbase = pos;    sl = s - 2048; }
    else               { xbase = neg;    sl = s - 4096; }
    const bool xact = (g4 < 2);
    const float* xp = xbase + (sl >> 7) * 131072 + (sl & 127) * 16 + (xact ? g4 * 8 : 0);

    float4 xa, xb, xa_n, xb_n;
    xa_n = make_float4(0.f, 0.f, 0.f, 0.f); xb_n = xa_n;
    if (xact) { xa = *(const float4*)(xp); xb = *(const float4*)(xp + 4); }
    else      { xa = xa_n; xb = xb_n; }

    float cst[4] = {0.f, 0.f, 0.f, 0.f};
    float hv[4]  = {0.f, 0.f, 0.f, 0.f};
    const int jw = wid * 16 + l15;
    int cur = 0;
    __syncthreads();

    for (int t = 0; t < 64; ++t) {
        if (xact && t < 63) {
            const float* p = xp + (t + 1) * 2048;
            xa_n = *(const float4*)(p); xb_n = *(const float4*)(p + 4);
        }
        bf16x8 ax;
        if (xact) {
            ax[0]=(__bf16)xa.x; ax[1]=(__bf16)xa.y; ax[2]=(__bf16)xa.z; ax[3]=(__bf16)xa.w;
            ax[4]=(__bf16)xb.x; ax[5]=(__bf16)xb.y; ax[6]=(__bf16)xb.z; ax[7]=(__bf16)xb.w;
        } else {
            #pragma unroll
            for (int i = 0; i < 8; ++i) ax[i] = (__bf16)0.f;
        }

        {
            const int m = l15;
            const int c0 = g4 * 2;
            const int swz = (m & 3) << 1;
            const unsigned int* hb = Hbuf[cur];
            uint4 v0 = *(const uint4*)(hb + m * 32 + ((c0 ^ swz) << 2));
            uint4 v1 = *(const uint4*)(hb + m * 32 + (((c0 + 1) ^ swz) << 2));
            union { unsigned int w[4]; bf16x8 v; } ahi, alo;
            ahi.w[0] = __builtin_amdgcn_perm(v0.y, v0.x, 0x05040100u);
            ahi.w[1] = __builtin_amdgcn_perm(v0.w, v0.z, 0x05040100u);
            ahi.w[2] = __builtin_amdgcn_perm(v1.y, v1.x, 0x05040100u);
            ahi.w[3] = __builtin_amdgcn_perm(v1.w, v1.z, 0x05040100u);
            alo.w[0] = __builtin_amdgcn_perm(v0.y, v0.x, 0x07060302u);
            alo.w[1] = __builtin_amdgcn_perm(v0.w, v0.z, 0x07060302u);
            alo.w[2] = __builtin_amdgcn_perm(v1.y, v1.x, 0x07060302u);
            alo.w[3] = __builtin_amdgcn_perm(v1.w, v1.z, 0x07060302u);

            f32x4 acc[4];
            #pragma unroll
            for (int q = 0; q < 4; ++q) {
                f32x4 a = __builtin_amdgcn_mfma_f32_16x16x32_bf16(ax,    wih_hi[q], bvec[q], 0, 0, 0);
                a = __builtin_amdgcn_mfma_f32_16x16x32_bf16(ax,    wih_lo[q], a, 0, 0, 0);
                a = __builtin_amdgcn_mfma_f32_16x16x32_bf16(ahi.v, whh_hi[q], a, 0, 0, 0);
                a = __builtin_amdgcn_mfma_f32_16x16x32_bf16(ahi.v, whh_lo[q], a, 0, 0, 0);
                a = __builtin_amdgcn_mfma_f32_16x16x32_bf16(alo.v, whh_hi[q], a, 0, 0, 0);
                acc[q] = a;
            }

            unsigned int* wb = Hbuf[cur ^ 1];
            #pragma unroll
            for (int r = 0; r < 4; ++r) {
                float zi = acc[0][r], zf = acc[1][r], zg = acc[2][r], zo = acc[3][r];
                float cn = fmaf(sigm(zf), cst[r], sigm(zi) * tanh_fast(zg));
                cst[r] = cn;
                float h = sigm(zo) * tanh_fast(cn);
                hv[r] = h;
                __bf16 hh = (__bf16)h;
                __bf16 hl = (__bf16)(h - (float)hh);
                unsigned int pk = (unsigned int)__builtin_bit_cast(unsigned short, hh)
                                | ((unsigned int)__builtin_bit_cast(unsigned short, hl) << 16);
                const int mm = g4 * 4 + r;
                const int sw = (mm & 3) << 1;
                wb[mm * 32 + (((jw >> 2) ^ sw) << 2) + (jw & 3)] = pk;
            }
        }
        __syncthreads();
        cur ^= 1;
        xa = xa_n; xb = xb_n;
    }

    #pragma unroll
    for (int r = 0; r < 4; ++r) {
        const int mm = g4 * 4 + r;
        hn[(blockIdx.x * 16 + mm) * 32 + jw] = hv[r];
    }
}

// ---------------------------------------------------------------------------
// GATv2 layer 1 (register-P): one block per (graph, head), 256 threads.
// thread = (d = tid>>1, s-half): 64 logits in VGPRs. lrelu split:
// a.lrelu(e) = 0.6 a.e + 0.4 a.|e|  ->  logit = 0.6(Ad+As) + sum 0.4a|fd+fs|.
// Tiles padded [128][36]: keeps b128 alignment, row-scans ~4-way max.
// ---------------------------------------------------------------------------
__global__ __launch_bounds__(256, 2) void gat1_kernel(
    const float* __restrict__ hn, const float* __restrict__ W1s,
    const float* __restrict__ W1d, const float* __restrict__ a1,
    const float* __restrict__ b1, float* __restrict__ h1heads)
{
    const int g = blockIdx.x >> 3, hd = blockIdx.x & 7;
    __shared__ float HS[128][36];
    __shared__ float FS[128][36];
    __shared__ float FD[128][36];
    __shared__ float WS[32][32];
    __shared__ float WD[32][32];
    __shared__ float AVr[32];
    __shared__ float As06[128];
    __shared__ float Ad06[128];
    const int tid = threadIdx.x;

    // stage h tile + weights
    {
        const float4* src = (const float4*)(hn + g * 4096);
        #pragma unroll
        for (int i = 0; i < 4; ++i) {
            int idx4 = i * 256 + tid;
            float4 v = src[idx4];
            int n = idx4 >> 3, k0 = (idx4 & 7) * 4;
            *(float4*)&HS[n][k0] = v;
        }
        const float4* ws4 = (const float4*)(W1s + hd * 1024);
        const float4* wd4 = (const float4*)(W1d + hd * 1024);
        float4 v = ws4[tid];
        int k = tid >> 3, o0 = (tid & 7) * 4;
        *(float4*)&WS[k][o0] = v;
        v = wd4[tid];
        *(float4*)&WD[k][o0] = v;
        if (tid < 32) AVr[tid] = a1[hd * 32 + tid];
    }
    __syncthreads();

    // fs = h@Ws, fd = h@Wd
    {
        const int o = tid & 31, nb = tid >> 5;
        float wcs[32], wcd[32];
        #pragma unroll
        for (int k = 0; k < 32; ++k) { wcs[k] = WS[k][o]; wcd[k] = WD[k][o]; }
        #pragma unroll 1
        for (int n = nb * 16; n < nb * 16 + 16; ++n) {
            float a0 = 0.f, a1_ = 0.f, b0 = 0.f, b1_ = 0.f;
            #pragma unroll
            for (int k0 = 0; k0 < 32; k0 += 4) {
                const float4 hv = *(const float4*)&HS[n][k0];
                a0 = fmaf(hv.x, wcs[k0+0], a0); b0 = fmaf(hv.x, wcd[k0+0], b0);
                a1_ = fmaf(hv.y, wcs[k0+1], a1_); b1_ = fmaf(hv.y, wcd[k0+1], b1_);
                a0 = fmaf(hv.z, wcs[k0+2], a0); b0 = fmaf(hv.z, wcd[k0+2], b0);
                a1_ = fmaf(hv.w, wcs[k0+3], a1_); b1_ = fmaf(hv.w, wcd[k0+3], b1_);
            }
            FS[n][o] = a0 + a1_;
            FD[n][o] = b0 + b1_;
        }
    }
    __syncthreads();

    // As06[s] = 0.6*dot(a, fs[s]);  Ad06[d] = 0.6*dot(a, fd[d])
    if (tid < 128) {
        float ss = 0.f, sd = 0.f;
        #pragma unroll
        for (int oo = 0; oo < 32; ++oo) {
            int o = (oo + tid) & 31;           // rotation: conflict-free
            float a = AVr[o];
            ss = fmaf(a, FS[tid][o], ss);
            sd = fmaf(a, FD[tid][o], sd);
        }
        As06[tid] = 0.6f * ss;
        Ad06[tid] = 0.6f * sd;
    }
    __syncthreads();

    const int d = tid >> 1, sbase = (tid & 1) << 6;
    float p[64];
    {
        float fdr[32], avs[32];
        #pragma unroll
        for (int c = 0; c < 8; ++c) {
            float4 v = *(const float4*)&FD[d][c * 4];
            fdr[c*4+0] = v.x; fdr[c*4+1] = v.y; fdr[c*4+2] = v.z; fdr[c*4+3] = v.w;
            float4 w = *(const float4*)&AVr[c * 4];
            avs[c*4+0] = 0.4f * w.x; avs[c*4+1] = 0.4f * w.y;
            avs[c*4+2] = 0.4f * w.z; avs[c*4+3] = 0.4f * w.w;
        }
        const float adc = Ad06[d];
        #pragma unroll
        for (int si = 0; si < 64; ++si) {
            const int s = sbase + si;
            float c0 = 0.f, c1 = 0.f, c2 = 0.f, c3 = 0.f;
            #pragma unroll
            for (int c = 0; c < 8; c += 2) {
                float4 fv = *(const float4*)&FS[s][c * 4];
                float e;
                e = fdr[c*4+0] + fv.x; c0 = fmaf(avs[c*4+0], __builtin_fabsf(e), c0);
                e = fdr[c*4+1] + fv.y; c1 = fmaf(avs[c*4+1], __builtin_fabsf(e), c1);
                e = fdr[c*4+2] + fv.z; c2 = fmaf(avs[c*4+2], __builtin_fabsf(e), c2);
                e = fdr[c*4+3] + fv.w; c3 = fmaf(avs[c*4+3], __builtin_fabsf(e), c3);
                float4 fw = *(const float4*)&FS[s][c * 4 + 4];
                e = fdr[c*4+4] + fw.x; c0 = fmaf(avs[c*4+4], __builtin_fabsf(e), c0);
                e = fdr[c*4+5] + fw.y; c1 = fmaf(avs[c*4+5], __builtin_fabsf(e), c1);
                e = fdr[c*4+6] + fw.z; c2 = fmaf(avs[c*4+6], __builtin_fabsf(e), c2);
                e = fdr[c*4+7] + fw.w; c3 = fmaf(avs[c*4+7], __builtin_fabsf(e), c3);
            }
            float v = adc + As06[s] + ((c0 + c1) + (c2 + c3));
            p[si] = (s == d) ? -1e30f : v;     // diagonal mask -> exp = 0
        }
    }
    // softmax (row split over lane pair)
    float m = -1e30f;
    #pragma unroll
    for (int si = 0; si < 64; ++si) m = fmaxf(m, p[si]);
    m = fmaxf(m, __shfl_xor(m, 1));
    float Z = 0.f;
    #pragma unroll
    for (int si = 0; si < 64; ++si) { float e = __expf(p[si] - m); p[si] = e; Z += e; }
    Z += __shfl_xor(Z, 1);
    const float rz = fast_rcp(Z);

    // PV: acc[o] = sum_s p[s] * fs[s][o]
    float acc[32];
    #pragma unroll
    for (int o = 0; o < 32; ++o) acc[o] = 0.f;
    #pragma unroll
    for (int k = 0; k < 64; ++k) {
        const float pk = p[k];
        const int s = sbase + k;
        #pragma unroll
        for (int c = 0; c < 8; ++c) {
            float4 fv = *(const float4*)&FS[s][c * 4];
            acc[c*4+0] = fmaf(pk, fv.x, acc[c*4+0]);
            acc[c*4+1] = fmaf(pk, fv.y, acc[c*4+1]);
            acc[c*4+2] = fmaf(pk, fv.z, acc[c*4+2]);
            acc[c*4+3] = fmaf(pk, fv.w, acc[c*4+3]);
        }
    }
    #pragma unroll
    for (int o = 0; o < 32; ++o) acc[o] += __shfl_xor(acc[o], 1);

    float* dst = h1heads + ((size_t)((g * 8 + hd) * 128 + d)) * 32;
    const float* bp = b1 + hd * 32;
    if ((tid & 1) == 0) {
        #pragma unroll
        for (int c = 0; c < 4; ++c) {
            float4 v;
            v.x = fmaf(acc[c*4+0], rz, bp[c*4+0]);
            v.y = fmaf(acc[c*4+1], rz, bp[c*4+1]);
            v.z = fmaf(acc[c*4+2], rz, bp[c*4+2]);
            v.w = fmaf(acc[c*4+3], rz, bp[c*4+3]);
            *(float4*)(dst + c * 4) = v;
        }
    } else {
        #pragma unroll
        for (int c = 4; c < 8; ++c) {
            float4 v;
            v.x = fmaf(acc[c*4+0], rz, bp[c*4+0]);
            v.y = fmaf(acc[c*4+1], rz, bp[c*4+1]);
            v.z = fmaf(acc[c*4+2], rz, bp[c*4+2]);
            v.w = fmaf(acc[c*4+3], rz, bp[c*4+3]);
            *(float4*)(dst + c * 4) = v;
        }
    }
}

// ---------------------------------------------------------------------------
// GATv2 layer 2 (register-P, same structure): one block per graph.
// Head-mean fused on load; FD reused as pooling buffer; writes pooled directly.
// ---------------------------------------------------------------------------
__global__ __launch_bounds__(256, 2) void gat2_kernel(
    const float* __restrict__ h1heads, const float* __restrict__ W2s,
    const float* __restrict__ W2d, const float* __restrict__ a2,
    const float* __restrict__ b2, float* __restrict__ pooled)
{
    const int g = blockIdx.x;
    __shared__ float HS[128][36];
    __shared__ float FS[128][36];
    __shared__ float FD[128][36];     // reused as OUT after logits
    __shared__ float WS[32][32];
    __shared__ float WD[32][32];
    __shared__ float AVr[32];
    __shared__ float As06[128];
    __shared__ float Ad06[128];
    const int tid = threadIdx.x;

    // stage: h1 = mean over 8 heads
    {
        #pragma unroll
        for (int i = 0; i < 4; ++i) {
            int idx4 = i * 256 + tid;
            float sx = 0.f, sy = 0.f, sz = 0.f, sw = 0.f;
            #pragma unroll
            for (int hdd = 0; hdd < 8; ++hdd) {
                const float4* src = (const float4*)(h1heads + (size_t)(g * 8 + hdd) * 4096);
                float4 v = src[idx4];
                sx += v.x; sy += v.y; sz += v.z; sw += v.w;
            }
            int n = idx4 >> 3, k0 = (idx4 & 7) * 4;
            float4 r; r.x = sx * 0.125f; r.y = sy * 0.125f; r.z = sz * 0.125f; r.w = sw * 0.125f;
            *(float4*)&HS[n][k0] = r;
        }
        const float4* ws4 = (const float4*)(W2s);
        const float4* wd4 = (const float4*)(W2d);
        float4 v = ws4[tid];
        int k = tid >> 3, o0 = (tid & 7) * 4;
        *(float4*)&WS[k][o0] = v;
        v = wd4[tid];
        *(float4*)&WD[k][o0] = v;
        if (tid < 32) AVr[tid] = a2[tid];
    }
    __syncthreads();

    {
        const int o = tid & 31, nb = tid >> 5;
        float wcs[32], wcd[32];
        #pragma unroll
        for (int k = 0; k < 32; ++k) { wcs[k] = WS[k][o]; wcd[k] = WD[k][o]; }
        #pragma unroll 1
        for (int n = nb * 16; n < nb * 16 + 16; ++n) {
            float a0 = 0.f, a1_ = 0.f, b0 = 0.f, b1_ = 0.f;
            #pragma unroll
            for (int k0 = 0; k0 < 32; k0 += 4) {
                const float4 hv = *(const float4*)&HS[n][k0];
                a0 = fmaf(hv.x, wcs[k0+0], a0); b0 = fmaf(hv.x, wcd[k0+0], b0);
                a1_ = fmaf(hv.y, wcs[k0+1], a1_); b1_ = fmaf(hv.y, wcd[k0+1], b1_);
                a0 = fmaf(hv.z, wcs[k0+2], a0); b0 = fmaf(hv.z, wcd[k0+2], b0);
                a1_ = fmaf(hv.w, wcs[k0+3], a1_); b1_ = fmaf(hv.w, wcd[k0+3], b1_);
            }
            FS[n][o] = a0 + a1_;
            FD[n][o] = b0 + b1_;
        }
    }
    __syncthreads();

    if (tid < 128) {
        float ss = 0.f, sd = 0.f;
        #pragma unroll
        for (int oo = 0; oo < 32; ++oo) {
            int o = (oo + tid) & 31;
            float a = AVr[o];
            ss = fmaf(a, FS[tid][o], ss);
            sd = fmaf(a, FD[tid][o], sd);
        }
        As06[tid] = 0.6f * ss;
        Ad06[tid] = 0.6f * sd;
    }
    __syncthreads();

    const int d = tid >> 1, sbase = (tid & 1) << 6;
    float p[64];
    {
        float fdr[32], avs[32];
        #pragma unroll
        for (int c = 0; c < 8; ++c) {
            float4 v = *(const float4*)&FD[d][c * 4];
            fdr[c*4+0] = v.x; fdr[c*4+1] = v.y; fdr[c*4+2] = v.z; fdr[c*4+3] = v.w;
            float4 w = *(const float4*)&AVr[c * 4];
            avs[c*4+0] = 0.4f * w.x; avs[c*4+1] = 0.4f * w.y;
            avs[c*4+2] = 0.4f * w.z; avs[c*4+3] = 0.4f * w.w;
        }
        const float adc = Ad06[d];
        #pragma unroll
        for (int si = 0; si < 64; ++si) {
            const int s = sbase + si;
            float c0 = 0.f, c1 = 0.f, c2 = 0.f, c3 = 0.f;
            #pragma unroll
            for (int c = 0; c < 8; c += 2) {
                float4 fv = *(const float4*)&FS[s][c * 4];
                float e;
                e = fdr[c*4+0] + fv.x; c0 = fmaf(avs[c*4+0], __builtin_fabsf(e), c0);
                e = fdr[c*4+1] + fv.y; c1 = fmaf(avs[c*4+1], __builtin_fabsf(e), c1);
                e = fdr[c*4+2] + fv.z; c2 = fmaf(avs[c*4+2], __builtin_fabsf(e), c2);
                e = fdr[c*4+3] + fv.w; c3 = fmaf(avs[c*4+3], __builtin_fabsf(e), c3);
                float4 fw = *(const float4*)&FS[s][c * 4 + 4];
                e = fdr[c*4+4] + fw.x; c0 = fmaf(avs[c*4+4], __builtin_fabsf(e), c0);
                e = fdr[c*4+5] + fw.y; c1 = fmaf(avs[c*4+5], __builtin_fabsf(e), c1);
                e = fdr[c*4+6] + fw.z; c2 = fmaf(avs[c*4+6], __builtin_fabsf(e), c2);
                e = fdr[c*4+7] + fw.w; c3 = fmaf(avs[c*4+7], __builtin_fabsf(e), c3);
            }
            float v = adc + As06[s] + ((c0 + c1) + (c2 + c3));
            p[si] = (s == d) ? -1e30f : v;
        }
    }
    float m = -1e30f;
    #pragma unroll
    for (int si = 0; si < 64; ++si) m = fmaxf(m, p[si]);
    m = fmaxf(m, __shfl_xor(m, 1));
    float Z = 0.f;
    #pragma unroll
    for (int si = 0; si < 64; ++si) { float e = __expf(p[si] - m); p[si] = e; Z += e; }
    Z += __shfl_xor(Z, 1);
    const float rz = fast_rcp(Z);

    float acc[32];
    #pragma unroll
    for (int o = 0; o < 32; ++o) acc[o] = 0.f;
    #pragma unroll
    for (int k = 0; k < 64; ++k) {
        const float pk = p[k];
        const int s = sbase + k;
        #pragma unroll
        for (int c = 0; c < 8; ++c) {
            float4 fv = *(const float4*)&FS[s][c * 4];
            acc[c*4+0] = fmaf(pk, fv.x, acc[c*4+0]);
            acc[c*4+1] = fmaf(pk, fv.y, acc[c*4+1]);
            acc[c*4+2] = fmaf(pk, fv.z, acc[c*4+2]);
            acc[c*4+3] = fmaf(pk, fv.w, acc[c*4+3]);
        }
    }
    #pragma unroll
    for (int o = 0; o < 32; ++o) acc[o] += __shfl_xor(acc[o], 1);

    __syncthreads();     // all FD (fdr) reads done -> safe to reuse FD as OUT
    if ((tid & 1) == 0) {
        #pragma unroll
        for (int c = 0; c < 4; ++c) {
            float4 v;
            v.x = acc[c*4+0] * rz; v.y = acc[c*4+1] * rz;
            v.z = acc[c*4+2] * rz; v.w = acc[c*4+3] * rz;
            *(float4*)&FD[d][c * 4] = v;
        }
    } else {
        #pragma unroll
        for (int c = 4; c < 8; ++c) {
            float4 v;
            v.x = acc[c*4+0] * rz; v.y = acc[c*4+1] * rz;
            v.z = acc[c*4+2] * rz; v.w = acc[c*4+3] * rz;
            *(float4*)&FD[d][c * 4] = v;
        }
    }
    __syncthreads();

    // pooled[g][o] = mean_n OUT[n][o] + b2[o]
    if (tid < 32) {
        float sp = 0.f;
        #pragma unroll 1
        for (int n = 0; n < 128; ++n) sp += FD[n][tid];
        pooled[g * 32 + tid] = fmaf(sp, 1.f / 128.f, b2[tid]);
    }
}

// ---------------------------------------------------------------------------
// Final: cosine sims, contrastive loss, output assembly.
// ---------------------------------------------------------------------------
__global__ void final_kernel(const float* __restrict__ pooled,
                             const float* __restrict__ hideout,
                             const float* __restrict__ timestep,
                             float* __restrict__ out)
{
    const int b = threadIdx.x;
    __shared__ float lossArr[16];
    if (b < 16) {
        const float* A  = pooled + b * 32;
        const float* Pv = pooled + (16 + b) * 32;
        float av[32];
        float na = 0.f;
        #pragma unroll
        for (int i = 0; i < 32; ++i) { av[i] = A[i]; na += av[i] * av[i]; }
        float npv = 0.f, dp = 0.f;
        #pragma unroll
        for (int i = 0; i < 32; ++i) { float p = Pv[i]; npv += p * p; dp += av[i] * p; }
        const float eps = 1e-6f;
        const float ia = 1.f / fmaxf(sqrtf(na), eps);
        const float sp = dp * ia / fmaxf(sqrtf(npv), eps);
        float sn[4];
        #pragma unroll
        for (int k = 0; k < 4; ++k) {
            const float* Nv = pooled + (32 + b * 4 + k) * 32;
            float nn = 0.f, dn = 0.f;
            #pragma unroll
            for (int i = 0; i < 32; ++i) { float q = Nv[i]; nn += q * q; dn += av[i] * q; }
            sn[k] = dn * ia / fmaxf(sqrtf(nn), eps);
        }
        float m = sp;
        #pragma unroll
        for (int k = 0; k < 4; ++k) m = fmaxf(m, sn[k]);
        float Z = expf(sp - m);
        #pragma unroll
        for (int k = 0; k < 4; ++k) Z += expf(sn[k] - m);
        lossArr[b] = logf(Z) + m - sp;
        float* r = out + b * 35;
        #pragma unroll
        for (int i = 0; i < 32; ++i) r[i] = av[i];
        r[32] = hideout[b * 2];
        r[33] = hideout[b * 2 + 1];
        r[34] = timestep[b];
    }
    __syncthreads();
    if (b == 0) {
        float s = 0.f;
        #pragma unroll
        for (int i = 0; i < 16; ++i) s += lossArr[i];
        out[560] = s * (1.f / 16.f);
    }
}

extern "C" void kernel_launch(void* const* d_in, const int* in_sizes, int n_in,
                              void* d_out, int out_size, void* d_ws, size_t ws_size,
                              hipStream_t stream) {
    const float* anchor   = (const float*)d_in[0];
    const float* pos      = (const float*)d_in[1];
    const float* neg      = (const float*)d_in[2];
    const float* hideout  = (const float*)d_in[3];
    const float* timestep = (const float*)d_in[4];
    const float* Wih      = (const float*)d_in[5];
    const float* Whh      = (const float*)d_in[6];
    const float* b_lstm   = (const float*)d_in[7];
    const float* W1s      = (const float*)d_in[8];
    const float* W1d      = (const float*)d_in[9];
    const float* a1       = (const float*)d_in[10];
    const float* b1       = (const float*)d_in[11];
    const float* W2s      = (const float*)d_in[12];
    const float* W2d      = (const float*)d_in[13];
    const float* a2       = (const float*)d_in[14];
    const float* b2       = (const float*)d_in[15];
    float* out = (float*)d_out;

    char* ws = (char*)d_ws;
    float* hn      = (float*)(ws);                       // 12288*32*4   = 1,572,864 B
    float* h1heads = (float*)(ws + 1605632);             // 96*8*128*32*4 = 12,582,912 B
    float* pooled  = (float*)(ws + 14188544);            // 96*32*4      = 12,288 B

    hipLaunchKernelGGL(lstm_mfma_kernel, dim3(768), dim3(128), 0, stream,
                       anchor, pos, neg, Wih, Whh, b_lstm, hn);
    hipLaunchKernelGGL(gat1_kernel,  dim3(768),  dim3(256), 0, stream,
                       hn, W1s, W1d, a1, b1, h1heads);
    hipLaunchKernelGGL(gat2_kernel,  dim3(96),   dim3(256), 0, stream,
                       h1heads, W2s, W2d, a2, b2, pooled);
    hipLaunchKernelGGL(final_kernel, dim3(1),    dim3(64),  0, stream,
                       pooled, hideout, timestep, out);
}

// Round 4
// 254.763 us; speedup vs baseline: 3.4037x; 3.4037x over previous
//
#include <hip/hip_runtime.h>
#include <math.h>

// Problem constants: B=16, K=4, T=64, N=128, F=16, H=32, NH=8, GH=32
// Sequences: 12288 = 2048 anchor + 2048 pos + 8192 neg. Graphs: 96 = 16+16+64.

typedef __bf16 bf16x8 __attribute__((ext_vector_type(8)));
typedef float  f32x4  __attribute__((ext_vector_type(4)));

__device__ __forceinline__ float fast_rcp(float x) { return __builtin_amdgcn_rcpf(x); }
__device__ __forceinline__ float sigm(float x)     { return fast_rcp(1.f + __expf(-x)); }
__device__ __forceinline__ float tanh_fast(float x){ return fmaf(2.f, fast_rcp(1.f + __expf(-2.f * x)), -1.f); }

// ---------------------------------------------------------------------------
// LSTM via MFMA (unchanged; passes at absmax 2.4e-4).
// ---------------------------------------------------------------------------
__global__ __launch_bounds__(128) void lstm_mfma_kernel(
    const float* __restrict__ anchor, const float* __restrict__ pos,
    const float* __restrict__ neg, const float* __restrict__ Wih,
    const float* __restrict__ Whh, const float* __restrict__ bias,
    float* __restrict__ hn)
{
    __shared__ unsigned int Hbuf[2][16 * 32];   // [dbuf][m][j] packed bf16 hi|lo
    const int tid  = threadIdx.x;
    const int lane = tid & 63;
    const int wid  = tid >> 6;
    const int l15  = lane & 15;
    const int g4   = lane >> 4;

    for (int i = tid; i < 2 * 16 * 32; i += 128) ((unsigned int*)Hbuf)[i] = 0u;

    bf16x8 whh_hi[4], whh_lo[4], wih_hi[4], wih_lo[4];
    f32x4 bvec[4];
    #pragma unroll
    for (int q = 0; q < 4; ++q) {
        const int c = q * 32 + wid * 16 + l15;
        const float bq = bias[c];
        bvec[q][0] = bq; bvec[q][1] = bq; bvec[q][2] = bq; bvec[q][3] = bq;
        const float* wr = Whh + c * 32 + g4 * 8;
        #pragma unroll
        for (int i = 0; i < 8; ++i) {
            float w = wr[i];
            __bf16 hi = (__bf16)w;
            whh_hi[q][i] = hi;
            whh_lo[q][i] = (__bf16)(w - (float)hi);
        }
        if (g4 < 2) {
            const float* wr2 = Wih + c * 16 + g4 * 8;
            #pragma unroll
            for (int i = 0; i < 8; ++i) {
                float w = wr2[i];
                __bf16 hi = (__bf16)w;
                wih_hi[q][i] = hi;
                wih_lo[q][i] = (__bf16)(w - (float)hi);
            }
        } else {
            #pragma unroll
            for (int i = 0; i < 8; ++i) {
                wih_hi[q][i] = (__bf16)0.f; wih_lo[q][i] = (__bf16)0.f;
            }
        }
    }

    const int s = blockIdx.x * 16 + l15;
    const float* xbase; int sl;
    if (s < 2048)      { xbase = anchor; sl = s; }
    else if (s < 4096) { xbase = pos;    sl = s - 2048; }
    else               { xbase = neg;    sl = s - 4096; }
    const bool xact = (g4 < 2);
    const float* xp = xbase + (sl >> 7) * 131072 + (sl & 127) * 16 + (xact ? g4 * 8 : 0);

    float4 xa, xb, xa_n, xb_n;
    xa_n = make_float4(0.f, 0.f, 0.f, 0.f); xb_n = xa_n;
    if (xact) { xa = *(const float4*)(xp); xb = *(const float4*)(xp + 4); }
    else      { xa = xa_n; xb = xb_n; }

    float cst[4] = {0.f, 0.f, 0.f, 0.f};
    float hv[4]  = {0.f, 0.f, 0.f, 0.f};
    const int jw = wid * 16 + l15;
    int cur = 0;
    __syncthreads();

    for (int t = 0; t < 64; ++t) {
        if (xact && t < 63) {
            const float* p = xp + (t + 1) * 2048;
            xa_n = *(const float4*)(p); xb_n = *(const float4*)(p + 4);
        }
        bf16x8 ax;
        if (xact) {
            ax[0]=(__bf16)xa.x; ax[1]=(__bf16)xa.y; ax[2]=(__bf16)xa.z; ax[3]=(__bf16)xa.w;
            ax[4]=(__bf16)xb.x; ax[5]=(__bf16)xb.y; ax[6]=(__bf16)xb.z; ax[7]=(__bf16)xb.w;
        } else {
            #pragma unroll
            for (int i = 0; i < 8; ++i) ax[i] = (__bf16)0.f;
        }

        {
            const int m = l15;
            const int c0 = g4 * 2;
            const int swz = (m & 3) << 1;
            const unsigned int* hb = Hbuf[cur];
            uint4 v0 = *(const uint4*)(hb + m * 32 + ((c0 ^ swz) << 2));
            uint4 v1 = *(const uint4*)(hb + m * 32 + (((c0 + 1) ^ swz) << 2));
            union { unsigned int w[4]; bf16x8 v; } ahi, alo;
            ahi.w[0] = __builtin_amdgcn_perm(v0.y, v0.x, 0x05040100u);
            ahi.w[1] = __builtin_amdgcn_perm(v0.w, v0.z, 0x05040100u);
            ahi.w[2] = __builtin_amdgcn_perm(v1.y, v1.x, 0x05040100u);
            ahi.w[3] = __builtin_amdgcn_perm(v1.w, v1.z, 0x05040100u);
            alo.w[0] = __builtin_amdgcn_perm(v0.y, v0.x, 0x07060302u);
            alo.w[1] = __builtin_amdgcn_perm(v0.w, v0.z, 0x07060302u);
            alo.w[2] = __builtin_amdgcn_perm(v1.y, v1.x, 0x07060302u);
            alo.w[3] = __builtin_amdgcn_perm(v1.w, v1.z, 0x07060302u);

            f32x4 acc[4];
            #pragma unroll
            for (int q = 0; q < 4; ++q) {
                f32x4 a = __builtin_amdgcn_mfma_f32_16x16x32_bf16(ax,    wih_hi[q], bvec[q], 0, 0, 0);
                a = __builtin_amdgcn_mfma_f32_16x16x32_bf16(ax,    wih_lo[q], a, 0, 0, 0);
                a = __builtin_amdgcn_mfma_f32_16x16x32_bf16(ahi.v, whh_hi[q], a, 0, 0, 0);
                a = __builtin_amdgcn_mfma_f32_16x16x32_bf16(ahi.v, whh_lo[q], a, 0, 0, 0);
                a = __builtin_amdgcn_mfma_f32_16x16x32_bf16(alo.v, whh_hi[q], a, 0, 0, 0);
                acc[q] = a;
            }

            unsigned int* wb = Hbuf[cur ^ 1];
            #pragma unroll
            for (int r = 0; r < 4; ++r) {
                float zi = acc[0][r], zf = acc[1][r], zg = acc[2][r], zo = acc[3][r];
                float cn = fmaf(sigm(zf), cst[r], sigm(zi) * tanh_fast(zg));
                cst[r] = cn;
                float h = sigm(zo) * tanh_fast(cn);
                hv[r] = h;
                __bf16 hh = (__bf16)h;
                __bf16 hl = (__bf16)(h - (float)hh);
                unsigned int pk = (unsigned int)__builtin_bit_cast(unsigned short, hh)
                                | ((unsigned int)__builtin_bit_cast(unsigned short, hl) << 16);
                const int mm = g4 * 4 + r;
                const int sw = (mm & 3) << 1;
                wb[mm * 32 + (((jw >> 2) ^ sw) << 2) + (jw & 3)] = pk;
            }
        }
        __syncthreads();
        cur ^= 1;
        xa = xa_n; xb = xb_n;
    }

    #pragma unroll
    for (int r = 0; r < 4; ++r) {
        const int mm = g4 * 4 + r;
        hn[(blockIdx.x * 16 + mm) * 32 + jw] = hv[r];
    }
}

// ---------------------------------------------------------------------------
// GATv2 layer 1, spill-free 2-pass: one block per (graph, head), 256 threads.
// thread = (d = tid>>1, s-half of 64). Pass 1 computes logits tracking only
// the max (no stores). Pass 2 recomputes each logit, exponentiates, and
// fuses PV using the FS registers already loaded. No p[] array -> no scratch.
// lrelu split: a.lrelu(e) = 0.6 a.e + 0.4 a.|e|.
// LDS: only FS/FD [128][36] + row dots (~38 KB) -> 3-4 blocks/CU.
// h rows and W columns read straight from global (L2-resident, broadcast).
// ---------------------------------------------------------------------------
__global__ __launch_bounds__(256) void gat1_kernel(
    const float* __restrict__ hn, const float* __restrict__ W1s,
    const float* __restrict__ W1d, const float* __restrict__ a1,
    const float* __restrict__ b1, float* __restrict__ h1heads)
{
    const int g = blockIdx.x >> 3, hd = blockIdx.x & 7;
    __shared__ float FS[128][36];
    __shared__ float FD[128][36];
    __shared__ float AVr[32];
    __shared__ float As06[128];
    __shared__ float Ad06[128];
    const int tid = threadIdx.x;

    if (tid < 32) AVr[tid] = a1[hd * 32 + tid];

    // Phase A: fs = h@Ws, fd = h@Wd. thread = (o, 16-row slab).
    {
        const int o = tid & 31, nb = tid >> 5;
        float wcs[32], wcd[32];
        const float* wsp = W1s + hd * 1024 + o;
        const float* wdp = W1d + hd * 1024 + o;
        #pragma unroll
        for (int k = 0; k < 32; ++k) { wcs[k] = wsp[k * 32]; wcd[k] = wdp[k * 32]; }
        const float* hp = hn + g * 4096 + nb * 512;
        #pragma unroll 1
        for (int n = 0; n < 16; ++n) {
            float a0 = 0.f, a1_ = 0.f, b0 = 0.f, b1_ = 0.f;
            #pragma unroll
            for (int k0 = 0; k0 < 32; k0 += 4) {
                float4 hv = *(const float4*)(hp + n * 32 + k0);
                a0 = fmaf(hv.x, wcs[k0+0], a0); b0 = fmaf(hv.x, wcd[k0+0], b0);
                a1_ = fmaf(hv.y, wcs[k0+1], a1_); b1_ = fmaf(hv.y, wcd[k0+1], b1_);
                a0 = fmaf(hv.z, wcs[k0+2], a0); b0 = fmaf(hv.z, wcd[k0+2], b0);
                a1_ = fmaf(hv.w, wcs[k0+3], a1_); b1_ = fmaf(hv.w, wcd[k0+3], b1_);
            }
            FS[nb * 16 + n][o] = a0 + a1_;
            FD[nb * 16 + n][o] = b0 + b1_;
        }
    }
    __syncthreads();

    // As06[s] = 0.6*dot(a, fs[s]);  Ad06[d] = 0.6*dot(a, fd[d])
    if (tid < 128) {
        float ss = 0.f, sd = 0.f;
        #pragma unroll
        for (int oo = 0; oo < 32; ++oo) {
            int o = (oo + tid) & 31;           // rotation: conflict-free
            float a = AVr[o];
            ss = fmaf(a, FS[tid][o], ss);
            sd = fmaf(a, FD[tid][o], sd);
        }
        As06[tid] = 0.6f * ss;
        Ad06[tid] = 0.6f * sd;
    }
    __syncthreads();

    const int d = tid >> 1, sbase = (tid & 1) << 6;
    float fdr[32], avs[32];
    #pragma unroll
    for (int c = 0; c < 8; ++c) {
        float4 v = *(const float4*)&FD[d][c * 4];
        fdr[c*4+0] = v.x; fdr[c*4+1] = v.y; fdr[c*4+2] = v.z; fdr[c*4+3] = v.w;
        float4 w = *(const float4*)&AVr[c * 4];
        avs[c*4+0] = 0.4f * w.x; avs[c*4+1] = 0.4f * w.y;
        avs[c*4+2] = 0.4f * w.z; avs[c*4+3] = 0.4f * w.w;
    }
    const float adc = Ad06[d];

    // Pass 1: row max only
    float m = -1e30f;
    #pragma unroll 1
    for (int si = 0; si < 64; ++si) {
        const int s = sbase + si;
        float4 fa[8];
        #pragma unroll
        for (int c = 0; c < 8; ++c) fa[c] = *(const float4*)&FS[s][c * 4];
        float c0 = 0.f, c1 = 0.f, c2 = 0.f, c3 = 0.f;
        #pragma unroll
        for (int c = 0; c < 8; ++c) {
            float e0 = fdr[c*4+0] + fa[c].x; c0 = fmaf(avs[c*4+0], __builtin_fabsf(e0), c0);
            float e1 = fdr[c*4+1] + fa[c].y; c1 = fmaf(avs[c*4+1], __builtin_fabsf(e1), c1);
            float e2 = fdr[c*4+2] + fa[c].z; c2 = fmaf(avs[c*4+2], __builtin_fabsf(e2), c2);
            float e3 = fdr[c*4+3] + fa[c].w; c3 = fmaf(avs[c*4+3], __builtin_fabsf(e3), c3);
        }
        float v = adc + As06[s] + ((c0 + c1) + (c2 + c3));
        m = (s == d) ? m : fmaxf(m, v);
    }
    m = fmaxf(m, __shfl_xor(m, 1));

    // Pass 2: recompute logit, exp, fused PV (reuse fa registers)
    float Z = 0.f;
    float acc[32];
    #pragma unroll
    for (int o = 0; o < 32; ++o) acc[o] = 0.f;
    #pragma unroll 1
    for (int si = 0; si < 64; ++si) {
        const int s = sbase + si;
        float4 fa[8];
        #pragma unroll
        for (int c = 0; c < 8; ++c) fa[c] = *(const float4*)&FS[s][c * 4];
        float c0 = 0.f, c1 = 0.f, c2 = 0.f, c3 = 0.f;
        #pragma unroll
        for (int c = 0; c < 8; ++c) {
            float e0 = fdr[c*4+0] + fa[c].x; c0 = fmaf(avs[c*4+0], __builtin_fabsf(e0), c0);
            float e1 = fdr[c*4+1] + fa[c].y; c1 = fmaf(avs[c*4+1], __builtin_fabsf(e1), c1);
            float e2 = fdr[c*4+2] + fa[c].z; c2 = fmaf(avs[c*4+2], __builtin_fabsf(e2), c2);
            float e3 = fdr[c*4+3] + fa[c].w; c3 = fmaf(avs[c*4+3], __builtin_fabsf(e3), c3);
        }
        float v = adc + As06[s] + ((c0 + c1) + (c2 + c3));
        float e = (s == d) ? 0.f : __expf(v - m);
        Z += e;
        #pragma unroll
        for (int c = 0; c < 8; ++c) {
            acc[c*4+0] = fmaf(e, fa[c].x, acc[c*4+0]);
            acc[c*4+1] = fmaf(e, fa[c].y, acc[c*4+1]);
            acc[c*4+2] = fmaf(e, fa[c].z, acc[c*4+2]);
            acc[c*4+3] = fmaf(e, fa[c].w, acc[c*4+3]);
        }
    }
    Z += __shfl_xor(Z, 1);
    const float rz = fast_rcp(Z);
    #pragma unroll
    for (int o = 0; o < 32; ++o) acc[o] += __shfl_xor(acc[o], 1);

    float* dst = h1heads + ((size_t)((g * 8 + hd) * 128 + d)) * 32;
    const float* bp = b1 + hd * 32;
    if ((tid & 1) == 0) {
        #pragma unroll
        for (int c = 0; c < 4; ++c) {
            float4 v;
            v.x = fmaf(acc[c*4+0], rz, bp[c*4+0]);
            v.y = fmaf(acc[c*4+1], rz, bp[c*4+1]);
            v.z = fmaf(acc[c*4+2], rz, bp[c*4+2]);
            v.w = fmaf(acc[c*4+3], rz, bp[c*4+3]);
            *(float4*)(dst + c * 4) = v;
        }
    } else {
        #pragma unroll
        for (int c = 4; c < 8; ++c) {
            float4 v;
            v.x = fmaf(acc[c*4+0], rz, bp[c*4+0]);
            v.y = fmaf(acc[c*4+1], rz, bp[c*4+1]);
            v.z = fmaf(acc[c*4+2], rz, bp[c*4+2]);
            v.w = fmaf(acc[c*4+3], rz, bp[c*4+3]);
            *(float4*)(dst + c * 4) = v;
        }
    }
}

// ---------------------------------------------------------------------------
// GATv2 layer 2, same spill-free 2-pass structure: one block per graph.
// Head-mean fused on load into HS; FD reused as OUT tile for pooling.
// ---------------------------------------------------------------------------
__global__ __launch_bounds__(256) void gat2_kernel(
    const float* __restrict__ h1heads, const float* __restrict__ W2s,
    const float* __restrict__ W2d, const float* __restrict__ a2,
    const float* __restrict__ b2, float* __restrict__ pooled)
{
    const int g = blockIdx.x;
    __shared__ float HS[128][36];
    __shared__ float FS[128][36];
    __shared__ float FD[128][36];     // reused as OUT after pass 2
    __shared__ float AVr[32];
    __shared__ float As06[128];
    __shared__ float Ad06[128];
    const int tid = threadIdx.x;

    if (tid < 32) AVr[tid] = a2[tid];

    // stage: h1 = mean over 8 heads
    {
        #pragma unroll
        for (int i = 0; i < 4; ++i) {
            int idx4 = i * 256 + tid;
            float sx = 0.f, sy = 0.f, sz = 0.f, sw = 0.f;
            #pragma unroll
            for (int hdd = 0; hdd < 8; ++hdd) {
                const float4* src = (const float4*)(h1heads + (size_t)(g * 8 + hdd) * 4096);
                float4 v = src[idx4];
                sx += v.x; sy += v.y; sz += v.z; sw += v.w;
            }
            int n = idx4 >> 3, k0 = (idx4 & 7) * 4;
            float4 r; r.x = sx * 0.125f; r.y = sy * 0.125f; r.z = sz * 0.125f; r.w = sw * 0.125f;
            *(float4*)&HS[n][k0] = r;
        }
    }
    __syncthreads();

    // Phase A
    {
        const int o = tid & 31, nb = tid >> 5;
        float wcs[32], wcd[32];
        const float* wsp = W2s + o;
        const float* wdp = W2d + o;
        #pragma unroll
        for (int k = 0; k < 32; ++k) { wcs[k] = wsp[k * 32]; wcd[k] = wdp[k * 32]; }
        #pragma unroll 1
        for (int n = nb * 16; n < nb * 16 + 16; ++n) {
            float a0 = 0.f, a1_ = 0.f, b0 = 0.f, b1_ = 0.f;
            #pragma unroll
            for (int k0 = 0; k0 < 32; k0 += 4) {
                const float4 hv = *(const float4*)&HS[n][k0];
                a0 = fmaf(hv.x, wcs[k0+0], a0); b0 = fmaf(hv.x, wcd[k0+0], b0);
                a1_ = fmaf(hv.y, wcs[k0+1], a1_); b1_ = fmaf(hv.y, wcd[k0+1], b1_);
                a0 = fmaf(hv.z, wcs[k0+2], a0); b0 = fmaf(hv.z, wcd[k0+2], b0);
                a1_ = fmaf(hv.w, wcs[k0+3], a1_); b1_ = fmaf(hv.w, wcd[k0+3], b1_);
            }
            FS[n][o] = a0 + a1_;
            FD[n][o] = b0 + b1_;
        }
    }
    __syncthreads();

    if (tid < 128) {
        float ss = 0.f, sd = 0.f;
        #pragma unroll
        for (int oo = 0; oo < 32; ++oo) {
            int o = (oo + tid) & 31;
            float a = AVr[o];
            ss = fmaf(a, FS[tid][o], ss);
            sd = fmaf(a, FD[tid][o], sd);
        }
        As06[tid] = 0.6f * ss;
        Ad06[tid] = 0.6f * sd;
    }
    __syncthreads();

    const int d = tid >> 1, sbase = (tid & 1) << 6;
    float fdr[32], avs[32];
    #pragma unroll
    for (int c = 0; c < 8; ++c) {
        float4 v = *(const float4*)&FD[d][c * 4];
        fdr[c*4+0] = v.x; fdr[c*4+1] = v.y; fdr[c*4+2] = v.z; fdr[c*4+3] = v.w;
        float4 w = *(const float4*)&AVr[c * 4];
        avs[c*4+0] = 0.4f * w.x; avs[c*4+1] = 0.4f * w.y;
        avs[c*4+2] = 0.4f * w.z; avs[c*4+3] = 0.4f * w.w;
    }
    const float adc = Ad06[d];

    float m = -1e30f;
    #pragma unroll 1
    for (int si = 0; si < 64; ++si) {
        const int s = sbase + si;
        float4 fa[8];
        #pragma unroll
        for (int c = 0; c < 8; ++c) fa[c] = *(const float4*)&FS[s][c * 4];
        float c0 = 0.f, c1 = 0.f, c2 = 0.f, c3 = 0.f;
        #pragma unroll
        for (int c = 0; c < 8; ++c) {
            float e0 = fdr[c*4+0] + fa[c].x; c0 = fmaf(avs[c*4+0], __builtin_fabsf(e0), c0);
            float e1 = fdr[c*4+1] + fa[c].y; c1 = fmaf(avs[c*4+1], __builtin_fabsf(e1), c1);
            float e2 = fdr[c*4+2] + fa[c].z; c2 = fmaf(avs[c*4+2], __builtin_fabsf(e2), c2);
            float e3 = fdr[c*4+3] + fa[c].w; c3 = fmaf(avs[c*4+3], __builtin_fabsf(e3), c3);
        }
        float v = adc + As06[s] + ((c0 + c1) + (c2 + c3));
        m = (s == d) ? m : fmaxf(m, v);
    }
    m = fmaxf(m, __shfl_xor(m, 1));

    float Z = 0.f;
    float acc[32];
    #pragma unroll
    for (int o = 0; o < 32; ++o) acc[o] = 0.f;
    #pragma unroll 1
    for (int si = 0; si < 64; ++si) {
        const int s = sbase + si;
        float4 fa[8];
        #pragma unroll
        for (int c = 0; c < 8; ++c) fa[c] = *(const float4*)&FS[s][c * 4];
        float c0 = 0.f, c1 = 0.f, c2 = 0.f, c3 = 0.f;
        #pragma unroll
        for (int c = 0; c < 8; ++c) {
            float e0 = fdr[c*4+0] + fa[c].x; c0 = fmaf(avs[c*4+0], __builtin_fabsf(e0), c0);
            float e1 = fdr[c*4+1] + fa[c].y; c1 = fmaf(avs[c*4+1], __builtin_fabsf(e1), c1);
            float e2 = fdr[c*4+2] + fa[c].z; c2 = fmaf(avs[c*4+2], __builtin_fabsf(e2), c2);
            float e3 = fdr[c*4+3] + fa[c].w; c3 = fmaf(avs[c*4+3], __builtin_fabsf(e3), c3);
        }
        float v = adc + As06[s] + ((c0 + c1) + (c2 + c3));
        float e = (s == d) ? 0.f : __expf(v - m);
        Z += e;
        #pragma unroll
        for (int c = 0; c < 8; ++c) {
            acc[c*4+0] = fmaf(e, fa[c].x, acc[c*4+0]);
            acc[c*4+1] = fmaf(e, fa[c].y, acc[c*4+1]);
            acc[c*4+2] = fmaf(e, fa[c].z, acc[c*4+2]);
            acc[c*4+3] = fmaf(e, fa[c].w, acc[c*4+3]);
        }
    }
    Z += __shfl_xor(Z, 1);
    const float rz = fast_rcp(Z);
    #pragma unroll
    for (int o = 0; o < 32; ++o) acc[o] += __shfl_xor(acc[o], 1);

    __syncthreads();     // all FD reads done -> safe to reuse FD as OUT
    if ((tid & 1) == 0) {
        #pragma unroll
        for (int c = 0; c < 4; ++c) {
            float4 v;
            v.x = acc[c*4+0] * rz; v.y = acc[c*4+1] * rz;
            v.z = acc[c*4+2] * rz; v.w = acc[c*4+3] * rz;
            *(float4*)&FD[d][c * 4] = v;
        }
    } else {
        #pragma unroll
        for (int c = 4; c < 8; ++c) {
            float4 v;
            v.x = acc[c*4+0] * rz; v.y = acc[c*4+1] * rz;
            v.z = acc[c*4+2] * rz; v.w = acc[c*4+3] * rz;
            *(float4*)&FD[d][c * 4] = v;
        }
    }
    __syncthreads();

    // pooled[g][o] = mean_n OUT[n][o] + b2[o]
    if (tid < 32) {
        float sp = 0.f;
        #pragma unroll 1
        for (int n = 0; n < 128; ++n) sp += FD[n][tid];
        pooled[g * 32 + tid] = fmaf(sp, 1.f / 128.f, b2[tid]);
    }
}

// ---------------------------------------------------------------------------
// Final: cosine sims, contrastive loss, output assembly.
// ---------------------------------------------------------------------------
__global__ void final_kernel(const float* __restrict__ pooled,
                             const float* __restrict__ hideout,
                             const float* __restrict__ timestep,
                             float* __restrict__ out)
{
    const int b = threadIdx.x;
    __shared__ float lossArr[16];
    if (b < 16) {
        const float* A  = pooled + b * 32;
        const float* Pv = pooled + (16 + b) * 32;
        float av[32];
        float na = 0.f;
        #pragma unroll
        for (int i = 0; i < 32; ++i) { av[i] = A[i]; na += av[i] * av[i]; }
        float npv = 0.f, dp = 0.f;
        #pragma unroll
        for (int i = 0; i < 32; ++i) { float p = Pv[i]; npv += p * p; dp += av[i] * p; }
        const float eps = 1e-6f;
        const float ia = 1.f / fmaxf(sqrtf(na), eps);
        const float sp = dp * ia / fmaxf(sqrtf(npv), eps);
        float sn[4];
        #pragma unroll
        for (int k = 0; k < 4; ++k) {
            const float* Nv = pooled + (32 + b * 4 + k) * 32;
            float nn = 0.f, dn = 0.f;
            #pragma unroll
            for (int i = 0; i < 32; ++i) { float q = Nv[i]; nn += q * q; dn += av[i] * q; }
            sn[k] = dn * ia / fmaxf(sqrtf(nn), eps);
        }
        float m = sp;
        #pragma unroll
        for (int k = 0; k < 4; ++k) m = fmaxf(m, sn[k]);
        float Z = expf(sp - m);
        #pragma unroll
        for (int k = 0; k < 4; ++k) Z += expf(sn[k] - m);
        lossArr[b] = logf(Z) + m - sp;
        float* r = out + b * 35;
        #pragma unroll
        for (int i = 0; i < 32; ++i) r[i] = av[i];
        r[32] = hideout[b * 2];
        r[33] = hideout[b * 2 + 1];
        r[34] = timestep[b];
    }
    __syncthreads();
    if (b == 0) {
        float s = 0.f;
        #pragma unroll
        for (int i = 0; i < 16; ++i) s += lossArr[i];
        out[560] = s * (1.f / 16.f);
    }
}

extern "C" void kernel_launch(void* const* d_in, const int* in_sizes, int n_in,
                              void* d_out, int out_size, void* d_ws, size_t ws_size,
                              hipStream_t stream) {
    const float* anchor   = (const float*)d_in[0];
    const float* pos      = (const float*)d_in[1];
    const float* neg      = (const float*)d_in[2];
    const float* hideout  = (const float*)d_in[3];
    const float* timestep = (const float*)d_in[4];
    const float* Wih      = (const float*)d_in[5];
    const float* Whh      = (const float*)d_in[6];
    const float* b_lstm   = (const float*)d_in[7];
    const float* W1s      = (const float*)d_in[8];
    const float* W1d      = (const float*)d_in[9];
    const float* a1       = (const float*)d_in[10];
    const float* b1       = (const float*)d_in[11];
    const float* W2s      = (const float*)d_in[12];
    const float* W2d      = (const float*)d_in[13];
    const float* a2       = (const float*)d_in[14];
    const float* b2       = (const float*)d_in[15];
    float* out = (float*)d_out;

    char* ws = (char*)d_ws;
    float* hn      = (float*)(ws);                       // 12288*32*4   = 1,572,864 B
    float* h1heads = (float*)(ws + 1605632);             // 96*8*128*32*4 = 12,582,912 B
    float* pooled  = (float*)(ws + 14188544);            // 96*32*4      = 12,288 B

    hipLaunchKernelGGL(lstm_mfma_kernel, dim3(768), dim3(128), 0, stream,
                       anchor, pos, neg, Wih, Whh, b_lstm, hn);
    hipLaunchKernelGGL(gat1_kernel,  dim3(768),  dim3(256), 0, stream,
                       hn, W1s, W1d, a1, b1, h1heads);
    hipLaunchKernelGGL(gat2_kernel,  dim3(96),   dim3(256), 0, stream,
                       h1heads, W2s, W2d, a2, b2, pooled);
    hipLaunchKernelGGL(final_kernel, dim3(1),    dim3(64),  0, stream,
                       pooled, hideout, timestep, out);
}

// Round 5
// 203.715 us; speedup vs baseline: 4.2566x; 1.2506x over previous
//
#include <hip/hip_runtime.h>
#include <math.h>

// Problem constants: B=16, K=4, T=64, N=128, F=16, H=32, NH=8, GH=32
// Sequences: 12288 = 2048 anchor + 2048 pos + 8192 neg. Graphs: 96 = 16+16+64.

typedef __bf16 bf16x8 __attribute__((ext_vector_type(8)));
typedef float  f32x4  __attribute__((ext_vector_type(4)));

__device__ __forceinline__ float fast_rcp(float x) { return __builtin_amdgcn_rcpf(x); }
__device__ __forceinline__ float sigm(float x)     { return fast_rcp(1.f + __expf(-x)); }
__device__ __forceinline__ float tanh_fast(float x){ return fmaf(2.f, fast_rcp(1.f + __expf(-2.f * x)), -1.f); }

// ---------------------------------------------------------------------------
// LSTM via MFMA (unchanged; passes at absmax 2.4e-4).
// ---------------------------------------------------------------------------
__global__ __launch_bounds__(128) void lstm_mfma_kernel(
    const float* __restrict__ anchor, const float* __restrict__ pos,
    const float* __restrict__ neg, const float* __restrict__ Wih,
    const float* __restrict__ Whh, const float* __restrict__ bias,
    float* __restrict__ hn)
{
    __shared__ unsigned int Hbuf[2][16 * 32];   // [dbuf][m][j] packed bf16 hi|lo
    const int tid  = threadIdx.x;
    const int lane = tid & 63;
    const int wid  = tid >> 6;
    const int l15  = lane & 15;
    const int g4   = lane >> 4;

    for (int i = tid; i < 2 * 16 * 32; i += 128) ((unsigned int*)Hbuf)[i] = 0u;

    bf16x8 whh_hi[4], whh_lo[4], wih_hi[4], wih_lo[4];
    f32x4 bvec[4];
    #pragma unroll
    for (int q = 0; q < 4; ++q) {
        const int c = q * 32 + wid * 16 + l15;
        const float bq = bias[c];
        bvec[q][0] = bq; bvec[q][1] = bq; bvec[q][2] = bq; bvec[q][3] = bq;
        const float* wr = Whh + c * 32 + g4 * 8;
        #pragma unroll
        for (int i = 0; i < 8; ++i) {
            float w = wr[i];
            __bf16 hi = (__bf16)w;
            whh_hi[q][i] = hi;
            whh_lo[q][i] = (__bf16)(w - (float)hi);
        }
        if (g4 < 2) {
            const float* wr2 = Wih + c * 16 + g4 * 8;
            #pragma unroll
            for (int i = 0; i < 8; ++i) {
                float w = wr2[i];
                __bf16 hi = (__bf16)w;
                wih_hi[q][i] = hi;
                wih_lo[q][i] = (__bf16)(w - (float)hi);
            }
        } else {
            #pragma unroll
            for (int i = 0; i < 8; ++i) {
                wih_hi[q][i] = (__bf16)0.f; wih_lo[q][i] = (__bf16)0.f;
            }
        }
    }

    const int s = blockIdx.x * 16 + l15;
    const float* xbase; int sl;
    if (s < 2048)      { xbase = anchor; sl = s; }
    else if (s < 4096) { xbase = pos;    sl = s - 2048; }
    else               { xbase = neg;    sl = s - 4096; }
    const bool xact = (g4 < 2);
    const float* xp = xbase + (sl >> 7) * 131072 + (sl & 127) * 16 + (xact ? g4 * 8 : 0);

    float4 xa, xb, xa_n, xb_n;
    xa_n = make_float4(0.f, 0.f, 0.f, 0.f); xb_n = xa_n;
    if (xact) { xa = *(const float4*)(xp); xb = *(const float4*)(xp + 4); }
    else      { xa = xa_n; xb = xb_n; }

    float cst[4] = {0.f, 0.f, 0.f, 0.f};
    float hv[4]  = {0.f, 0.f, 0.f, 0.f};
    const int jw = wid * 16 + l15;
    int cur = 0;
    __syncthreads();

    for (int t = 0; t < 64; ++t) {
        if (xact && t < 63) {
            const float* p = xp + (t + 1) * 2048;
            xa_n = *(const float4*)(p); xb_n = *(const float4*)(p + 4);
        }
        bf16x8 ax;
        if (xact) {
            ax[0]=(__bf16)xa.x; ax[1]=(__bf16)xa.y; ax[2]=(__bf16)xa.z; ax[3]=(__bf16)xa.w;
            ax[4]=(__bf16)xb.x; ax[5]=(__bf16)xb.y; ax[6]=(__bf16)xb.z; ax[7]=(__bf16)xb.w;
        } else {
            #pragma unroll
            for (int i = 0; i < 8; ++i) ax[i] = (__bf16)0.f;
        }

        {
            const int m = l15;
            const int c0 = g4 * 2;
            const int swz = (m & 3) << 1;
            const unsigned int* hb = Hbuf[cur];
            uint4 v0 = *(const uint4*)(hb + m * 32 + ((c0 ^ swz) << 2));
            uint4 v1 = *(const uint4*)(hb + m * 32 + (((c0 + 1) ^ swz) << 2));
            union { unsigned int w[4]; bf16x8 v; } ahi, alo;
            ahi.w[0] = __builtin_amdgcn_perm(v0.y, v0.x, 0x05040100u);
            ahi.w[1] = __builtin_amdgcn_perm(v0.w, v0.z, 0x05040100u);
            ahi.w[2] = __builtin_amdgcn_perm(v1.y, v1.x, 0x05040100u);
            ahi.w[3] = __builtin_amdgcn_perm(v1.w, v1.z, 0x05040100u);
            alo.w[0] = __builtin_amdgcn_perm(v0.y, v0.x, 0x07060302u);
            alo.w[1] = __builtin_amdgcn_perm(v0.w, v0.z, 0x07060302u);
            alo.w[2] = __builtin_amdgcn_perm(v1.y, v1.x, 0x07060302u);
            alo.w[3] = __builtin_amdgcn_perm(v1.w, v1.z, 0x07060302u);

            f32x4 acc[4];
            #pragma unroll
            for (int q = 0; q < 4; ++q) {
                f32x4 a = __builtin_amdgcn_mfma_f32_16x16x32_bf16(ax,    wih_hi[q], bvec[q], 0, 0, 0);
                a = __builtin_amdgcn_mfma_f32_16x16x32_bf16(ax,    wih_lo[q], a, 0, 0, 0);
                a = __builtin_amdgcn_mfma_f32_16x16x32_bf16(ahi.v, whh_hi[q], a, 0, 0, 0);
                a = __builtin_amdgcn_mfma_f32_16x16x32_bf16(ahi.v, whh_lo[q], a, 0, 0, 0);
                a = __builtin_amdgcn_mfma_f32_16x16x32_bf16(alo.v, whh_hi[q], a, 0, 0, 0);
                acc[q] = a;
            }

            unsigned int* wb = Hbuf[cur ^ 1];
            #pragma unroll
            for (int r = 0; r < 4; ++r) {
                float zi = acc[0][r], zf = acc[1][r], zg = acc[2][r], zo = acc[3][r];
                float cn = fmaf(sigm(zf), cst[r], sigm(zi) * tanh_fast(zg));
                cst[r] = cn;
                float h = sigm(zo) * tanh_fast(cn);
                hv[r] = h;
                __bf16 hh = (__bf16)h;
                __bf16 hl = (__bf16)(h - (float)hh);
                unsigned int pk = (unsigned int)__builtin_bit_cast(unsigned short, hh)
                                | ((unsigned int)__builtin_bit_cast(unsigned short, hl) << 16);
                const int mm = g4 * 4 + r;
                const int sw = (mm & 3) << 1;
                wb[mm * 32 + (((jw >> 2) ^ sw) << 2) + (jw & 3)] = pk;
            }
        }
        __syncthreads();
        cur ^= 1;
        xa = xa_n; xb = xb_n;
    }

    #pragma unroll
    for (int r = 0; r < 4; ++r) {
        const int mm = g4 * 4 + r;
        hn[(blockIdx.x * 16 + mm) * 32 + jw] = hv[r];
    }
}

// ---------------------------------------------------------------------------
// GATv2 layer 1, single-pass (no max subtraction): logits are structurally
// bounded (|h|<1, W~1/sqrt(32) -> |logit| ~ O(5) << 88), so softmax without
// the max shift is mathematically identical and fp32-safe. One fused
// traversal: logit -> exp -> Z -> PV on the already-loaded FS registers.
// thread = (d = tid>>1, s-half of 64). No p[] array -> no scratch.
// lrelu split: a.lrelu(e) = 0.6 a.e + 0.4 a.|e|.
// ---------------------------------------------------------------------------
__global__ __launch_bounds__(256) void gat1_kernel(
    const float* __restrict__ hn, const float* __restrict__ W1s,
    const float* __restrict__ W1d, const float* __restrict__ a1,
    const float* __restrict__ b1, float* __restrict__ h1heads)
{
    const int g = blockIdx.x >> 3, hd = blockIdx.x & 7;
    __shared__ float FS[128][36];
    __shared__ float FD[128][36];
    __shared__ float AVr[32];
    __shared__ float As06[128];
    __shared__ float Ad06[128];
    const int tid = threadIdx.x;

    if (tid < 32) AVr[tid] = a1[hd * 32 + tid];

    // Phase A: fs = h@Ws, fd = h@Wd. thread = (o, 16-row slab).
    {
        const int o = tid & 31, nb = tid >> 5;
        float wcs[32], wcd[32];
        const float* wsp = W1s + hd * 1024 + o;
        const float* wdp = W1d + hd * 1024 + o;
        #pragma unroll
        for (int k = 0; k < 32; ++k) { wcs[k] = wsp[k * 32]; wcd[k] = wdp[k * 32]; }
        const float* hp = hn + g * 4096 + nb * 512;
        #pragma unroll 1
        for (int n = 0; n < 16; ++n) {
            float a0 = 0.f, a1_ = 0.f, b0 = 0.f, b1_ = 0.f;
            #pragma unroll
            for (int k0 = 0; k0 < 32; k0 += 4) {
                float4 hv = *(const float4*)(hp + n * 32 + k0);
                a0 = fmaf(hv.x, wcs[k0+0], a0); b0 = fmaf(hv.x, wcd[k0+0], b0);
                a1_ = fmaf(hv.y, wcs[k0+1], a1_); b1_ = fmaf(hv.y, wcd[k0+1], b1_);
                a0 = fmaf(hv.z, wcs[k0+2], a0); b0 = fmaf(hv.z, wcd[k0+2], b0);
                a1_ = fmaf(hv.w, wcs[k0+3], a1_); b1_ = fmaf(hv.w, wcd[k0+3], b1_);
            }
            FS[nb * 16 + n][o] = a0 + a1_;
            FD[nb * 16 + n][o] = b0 + b1_;
        }
    }
    __syncthreads();

    // As06[s] = 0.6*dot(a, fs[s]);  Ad06[d] = 0.6*dot(a, fd[d])
    if (tid < 128) {
        float ss = 0.f, sd = 0.f;
        #pragma unroll
        for (int oo = 0; oo < 32; ++oo) {
            int o = (oo + tid) & 31;           // rotation: conflict-free
            float a = AVr[o];
            ss = fmaf(a, FS[tid][o], ss);
            sd = fmaf(a, FD[tid][o], sd);
        }
        As06[tid] = 0.6f * ss;
        Ad06[tid] = 0.6f * sd;
    }
    __syncthreads();

    const int d = tid >> 1, sbase = (tid & 1) << 6;
    float fdr[32], avs[32];
    #pragma unroll
    for (int c = 0; c < 8; ++c) {
        float4 v = *(const float4*)&FD[d][c * 4];
        fdr[c*4+0] = v.x; fdr[c*4+1] = v.y; fdr[c*4+2] = v.z; fdr[c*4+3] = v.w;
        float4 w = *(const float4*)&AVr[c * 4];
        avs[c*4+0] = 0.4f * w.x; avs[c*4+1] = 0.4f * w.y;
        avs[c*4+2] = 0.4f * w.z; avs[c*4+3] = 0.4f * w.w;
    }
    const float adc = Ad06[d];

    // Single fused pass: logit -> exp -> Z -> PV (reuse fa registers)
    float Z = 0.f;
    float acc[32];
    #pragma unroll
    for (int o = 0; o < 32; ++o) acc[o] = 0.f;
    #pragma unroll 1
    for (int si = 0; si < 64; ++si) {
        const int s = sbase + si;
        float4 fa[8];
        #pragma unroll
        for (int c = 0; c < 8; ++c) fa[c] = *(const float4*)&FS[s][c * 4];
        float c0 = 0.f, c1 = 0.f, c2 = 0.f, c3 = 0.f;
        #pragma unroll
        for (int c = 0; c < 8; ++c) {
            float e0 = fdr[c*4+0] + fa[c].x; c0 = fmaf(avs[c*4+0], __builtin_fabsf(e0), c0);
            float e1 = fdr[c*4+1] + fa[c].y; c1 = fmaf(avs[c*4+1], __builtin_fabsf(e1), c1);
            float e2 = fdr[c*4+2] + fa[c].z; c2 = fmaf(avs[c*4+2], __builtin_fabsf(e2), c2);
            float e3 = fdr[c*4+3] + fa[c].w; c3 = fmaf(avs[c*4+3], __builtin_fabsf(e3), c3);
        }
        float v = adc + As06[s] + ((c0 + c1) + (c2 + c3));
        float e = (s == d) ? 0.f : __expf(v);
        Z += e;
        #pragma unroll
        for (int c = 0; c < 8; ++c) {
            acc[c*4+0] = fmaf(e, fa[c].x, acc[c*4+0]);
            acc[c*4+1] = fmaf(e, fa[c].y, acc[c*4+1]);
            acc[c*4+2] = fmaf(e, fa[c].z, acc[c*4+2]);
            acc[c*4+3] = fmaf(e, fa[c].w, acc[c*4+3]);
        }
    }
    Z += __shfl_xor(Z, 1);
    const float rz = fast_rcp(Z);
    #pragma unroll
    for (int o = 0; o < 32; ++o) acc[o] += __shfl_xor(acc[o], 1);

    float* dst = h1heads + ((size_t)((g * 8 + hd) * 128 + d)) * 32;
    const float* bp = b1 + hd * 32;
    if ((tid & 1) == 0) {
        #pragma unroll
        for (int c = 0; c < 4; ++c) {
            float4 v;
            v.x = fmaf(acc[c*4+0], rz, bp[c*4+0]);
            v.y = fmaf(acc[c*4+1], rz, bp[c*4+1]);
            v.z = fmaf(acc[c*4+2], rz, bp[c*4+2]);
            v.w = fmaf(acc[c*4+3], rz, bp[c*4+3]);
            *(float4*)(dst + c * 4) = v;
        }
    } else {
        #pragma unroll
        for (int c = 4; c < 8; ++c) {
            float4 v;
            v.x = fmaf(acc[c*4+0], rz, bp[c*4+0]);
            v.y = fmaf(acc[c*4+1], rz, bp[c*4+1]);
            v.z = fmaf(acc[c*4+2], rz, bp[c*4+2]);
            v.w = fmaf(acc[c*4+3], rz, bp[c*4+3]);
            *(float4*)(dst + c * 4) = v;
        }
    }
}

// ---------------------------------------------------------------------------
// GATv2 layer 2, same single-pass structure: one block per graph.
// Head-mean fused on load into HS; FD reused as OUT tile for pooling.
// ---------------------------------------------------------------------------
__global__ __launch_bounds__(256) void gat2_kernel(
    const float* __restrict__ h1heads, const float* __restrict__ W2s,
    const float* __restrict__ W2d, const float* __restrict__ a2,
    const float* __restrict__ b2, float* __restrict__ pooled)
{
    const int g = blockIdx.x;
    __shared__ float HS[128][36];
    __shared__ float FS[128][36];
    __shared__ float FD[128][36];     // reused as OUT after the fused pass
    __shared__ float AVr[32];
    __shared__ float As06[128];
    __shared__ float Ad06[128];
    const int tid = threadIdx.x;

    if (tid < 32) AVr[tid] = a2[tid];

    // stage: h1 = mean over 8 heads
    {
        #pragma unroll
        for (int i = 0; i < 4; ++i) {
            int idx4 = i * 256 + tid;
            float sx = 0.f, sy = 0.f, sz = 0.f, sw = 0.f;
            #pragma unroll
            for (int hdd = 0; hdd < 8; ++hdd) {
                const float4* src = (const float4*)(h1heads + (size_t)(g * 8 + hdd) * 4096);
                float4 v = src[idx4];
                sx += v.x; sy += v.y; sz += v.z; sw += v.w;
            }
            int n = idx4 >> 3, k0 = (idx4 & 7) * 4;
            float4 r; r.x = sx * 0.125f; r.y = sy * 0.125f; r.z = sz * 0.125f; r.w = sw * 0.125f;
            *(float4*)&HS[n][k0] = r;
        }
    }
    __syncthreads();

    // Phase A
    {
        const int o = tid & 31, nb = tid >> 5;
        float wcs[32], wcd[32];
        const float* wsp = W2s + o;
        const float* wdp = W2d + o;
        #pragma unroll
        for (int k = 0; k < 32; ++k) { wcs[k] = wsp[k * 32]; wcd[k] = wdp[k * 32]; }
        #pragma unroll 1
        for (int n = nb * 16; n < nb * 16 + 16; ++n) {
            float a0 = 0.f, a1_ = 0.f, b0 = 0.f, b1_ = 0.f;
            #pragma unroll
            for (int k0 = 0; k0 < 32; k0 += 4) {
                const float4 hv = *(const float4*)&HS[n][k0];
                a0 = fmaf(hv.x, wcs[k0+0], a0); b0 = fmaf(hv.x, wcd[k0+0], b0);
                a1_ = fmaf(hv.y, wcs[k0+1], a1_); b1_ = fmaf(hv.y, wcd[k0+1], b1_);
                a0 = fmaf(hv.z, wcs[k0+2], a0); b0 = fmaf(hv.z, wcd[k0+2], b0);
                a1_ = fmaf(hv.w, wcs[k0+3], a1_); b1_ = fmaf(hv.w, wcd[k0+3], b1_);
            }
            FS[n][o] = a0 + a1_;
            FD[n][o] = b0 + b1_;
        }
    }
    __syncthreads();

    if (tid < 128) {
        float ss = 0.f, sd = 0.f;
        #pragma unroll
        for (int oo = 0; oo < 32; ++oo) {
            int o = (oo + tid) & 31;
            float a = AVr[o];
            ss = fmaf(a, FS[tid][o], ss);
            sd = fmaf(a, FD[tid][o], sd);
        }
        As06[tid] = 0.6f * ss;
        Ad06[tid] = 0.6f * sd;
    }
    __syncthreads();

    const int d = tid >> 1, sbase = (tid & 1) << 6;
    float fdr[32], avs[32];
    #pragma unroll
    for (int c = 0; c < 8; ++c) {
        float4 v = *(const float4*)&FD[d][c * 4];
        fdr[c*4+0] = v.x; fdr[c*4+1] = v.y; fdr[c*4+2] = v.z; fdr[c*4+3] = v.w;
        float4 w = *(const float4*)&AVr[c * 4];
        avs[c*4+0] = 0.4f * w.x; avs[c*4+1] = 0.4f * w.y;
        avs[c*4+2] = 0.4f * w.z; avs[c*4+3] = 0.4f * w.w;
    }
    const float adc = Ad06[d];

    float Z = 0.f;
    float acc[32];
    #pragma unroll
    for (int o = 0; o < 32; ++o) acc[o] = 0.f;
    #pragma unroll 1
    for (int si = 0; si < 64; ++si) {
        const int s = sbase + si;
        float4 fa[8];
        #pragma unroll
        for (int c = 0; c < 8; ++c) fa[c] = *(const float4*)&FS[s][c * 4];
        float c0 = 0.f, c1 = 0.f, c2 = 0.f, c3 = 0.f;
        #pragma unroll
        for (int c = 0; c < 8; ++c) {
            float e0 = fdr[c*4+0] + fa[c].x; c0 = fmaf(avs[c*4+0], __builtin_fabsf(e0), c0);
            float e1 = fdr[c*4+1] + fa[c].y; c1 = fmaf(avs[c*4+1], __builtin_fabsf(e1), c1);
            float e2 = fdr[c*4+2] + fa[c].z; c2 = fmaf(avs[c*4+2], __builtin_fabsf(e2), c2);
            float e3 = fdr[c*4+3] + fa[c].w; c3 = fmaf(avs[c*4+3], __builtin_fabsf(e3), c3);
        }
        float v = adc + As06[s] + ((c0 + c1) + (c2 + c3));
        float e = (s == d) ? 0.f : __expf(v);
        Z += e;
        #pragma unroll
        for (int c = 0; c < 8; ++c) {
            acc[c*4+0] = fmaf(e, fa[c].x, acc[c*4+0]);
            acc[c*4+1] = fmaf(e, fa[c].y, acc[c*4+1]);
            acc[c*4+2] = fmaf(e, fa[c].z, acc[c*4+2]);
            acc[c*4+3] = fmaf(e, fa[c].w, acc[c*4+3]);
        }
    }
    Z += __shfl_xor(Z, 1);
    const float rz = fast_rcp(Z);
    #pragma unroll
    for (int o = 0; o < 32; ++o) acc[o] += __shfl_xor(acc[o], 1);

    __syncthreads();     // all FD reads done -> safe to reuse FD as OUT
    if ((tid & 1) == 0) {
        #pragma unroll
        for (int c = 0; c < 4; ++c) {
            float4 v;
            v.x = acc[c*4+0] * rz; v.y = acc[c*4+1] * rz;
            v.z = acc[c*4+2] * rz; v.w = acc[c*4+3] * rz;
            *(float4*)&FD[d][c * 4] = v;
        }
    } else {
        #pragma unroll
        for (int c = 4; c < 8; ++c) {
            float4 v;
            v.x = acc[c*4+0] * rz; v.y = acc[c*4+1] * rz;
            v.z = acc[c*4+2] * rz; v.w = acc[c*4+3] * rz;
            *(float4*)&FD[d][c * 4] = v;
        }
    }
    __syncthreads();

    // pooled[g][o] = mean_n OUT[n][o] + b2[o]
    if (tid < 32) {
        float sp = 0.f;
        #pragma unroll 1
        for (int n = 0; n < 128; ++n) sp += FD[n][tid];
        pooled[g * 32 + tid] = fmaf(sp, 1.f / 128.f, b2[tid]);
    }
}

// ---------------------------------------------------------------------------
// Final: cosine sims, contrastive loss, output assembly.
// ---------------------------------------------------------------------------
__global__ void final_kernel(const float* __restrict__ pooled,
                             const float* __restrict__ hideout,
                             const float* __restrict__ timestep,
                             float* __restrict__ out)
{
    const int b = threadIdx.x;
    __shared__ float lossArr[16];
    if (b < 16) {
        const float* A  = pooled + b * 32;
        const float* Pv = pooled + (16 + b) * 32;
        float av[32];
        float na = 0.f;
        #pragma unroll
        for (int i = 0; i < 32; ++i) { av[i] = A[i]; na += av[i] * av[i]; }
        float npv = 0.f, dp = 0.f;
        #pragma unroll
        for (int i = 0; i < 32; ++i) { float p = Pv[i]; npv += p * p; dp += av[i] * p; }
        const float eps = 1e-6f;
        const float ia = 1.f / fmaxf(sqrtf(na), eps);
        const float sp = dp * ia / fmaxf(sqrtf(npv), eps);
        float sn[4];
        #pragma unroll
        for (int k = 0; k < 4; ++k) {
            const float* Nv = pooled + (32 + b * 4 + k) * 32;
            float nn = 0.f, dn = 0.f;
            #pragma unroll
            for (int i = 0; i < 32; ++i) { float q = Nv[i]; nn += q * q; dn += av[i] * q; }
            sn[k] = dn * ia / fmaxf(sqrtf(nn), eps);
        }
        float m = sp;
        #pragma unroll
        for (int k = 0; k < 4; ++k) m = fmaxf(m, sn[k]);
        float Z = expf(sp - m);
        #pragma unroll
        for (int k = 0; k < 4; ++k) Z += expf(sn[k] - m);
        lossArr[b] = logf(Z) + m - sp;
        float* r = out + b * 35;
        #pragma unroll
        for (int i = 0; i < 32; ++i) r[i] = av[i];
        r[32] = hideout[b * 2];
        r[33] = hideout[b * 2 + 1];
        r[34] = timestep[b];
    }
    __syncthreads();
    if (b == 0) {
        float s = 0.f;
        #pragma unroll
        for (int i = 0; i < 16; ++i) s += lossArr[i];
        out[560] = s * (1.f / 16.f);
    }
}

extern "C" void kernel_launch(void* const* d_in, const int* in_sizes, int n_in,
                              void* d_out, int out_size, void* d_ws, size_t ws_size,
                              hipStream_t stream) {
    const float* anchor   = (const float*)d_in[0];
    const float* pos      = (const float*)d_in[1];
    const float* neg      = (const float*)d_in[2];
    const float* hideout  = (const float*)d_in[3];
    const float* timestep = (const float*)d_in[4];
    const float* Wih      = (const float*)d_in[5];
    const float* Whh      = (const float*)d_in[6];
    const float* b_lstm   = (const float*)d_in[7];
    const float* W1s      = (const float*)d_in[8];
    const float* W1d      = (const float*)d_in[9];
    const float* a1       = (const float*)d_in[10];
    const float* b1       = (const float*)d_in[11];
    const float* W2s      = (const float*)d_in[12];
    const float* W2d      = (const float*)d_in[13];
    const float* a2       = (const float*)d_in[14];
    const float* b2       = (const float*)d_in[15];
    float* out = (float*)d_out;

    char* ws = (char*)d_ws;
    float* hn      = (float*)(ws);                       // 12288*32*4   = 1,572,864 B
    float* h1heads = (float*)(ws + 1605632);             // 96*8*128*32*4 = 12,582,912 B
    float* pooled  = (float*)(ws + 14188544);            // 96*32*4      = 12,288 B

    hipLaunchKernelGGL(lstm_mfma_kernel, dim3(768), dim3(128), 0, stream,
                       anchor, pos, neg, Wih, Whh, b_lstm, hn);
    hipLaunchKernelGGL(gat1_kernel,  dim3(768),  dim3(256), 0, stream,
                       hn, W1s, W1d, a1, b1, h1heads);
    hipLaunchKernelGGL(gat2_kernel,  dim3(96),   dim3(256), 0, stream,
                       h1heads, W2s, W2d, a2, b2, pooled);
    hipLaunchKernelGGL(final_kernel, dim3(1),    dim3(64),  0, stream,
                       pooled, hideout, timestep, out);
}

// Round 6
// 192.162 us; speedup vs baseline: 4.5125x; 1.0601x over previous
//
#include <hip/hip_runtime.h>
#include <math.h>

// Problem constants: B=16, K=4, T=64, N=128, F=16, H=32, NH=8, GH=32
// Sequences: 12288 = 2048 anchor + 2048 pos + 8192 neg. Graphs: 96 = 16+16+64.

typedef __bf16 bf16x8 __attribute__((ext_vector_type(8)));
typedef float  f32x4  __attribute__((ext_vector_type(4)));

__device__ __forceinline__ float fast_rcp(float x) { return __builtin_amdgcn_rcpf(x); }
__device__ __forceinline__ float sigm(float x)     { return fast_rcp(1.f + __expf(-x)); }
__device__ __forceinline__ float tanh_fast(float x){ return fmaf(2.f, fast_rcp(1.f + __expf(-2.f * x)), -1.f); }

// ---------------------------------------------------------------------------
// LSTM via MFMA, barrier-free single-wave recurrence.
// Each wave owns 16 sequences and ALL 128 gate outputs (8 tiles of 16 cols):
// the per-step h transpose (C/D layout -> A-fragment layout) goes through a
// wave-PRIVATE LDS region, so ordering is guaranteed by the per-wave DS FIFO
// (no __syncthreads anywhere in the T-loop). x is prefetched 2 steps ahead
// (A/B register pairs, loop unrolled x2) to cover ~900cy HBM latency.
// Tile f = G*2+Hh: output col c = G*32 + Hh*16 + (lane&15), G=gate(i,f,g,o).
// C/D layout col=lane&15, row=(lane>>4)*4+reg [HW-verified]; k-slot
// convention k=8*(lane>>4)+i identical for A and B -> permutation-invariant.
// Precision: W and h carried as bf16 hi+lo pairs (5 MFMAs/tile).
// ---------------------------------------------------------------------------
__device__ __forceinline__ void lstm_step(
    const bf16x8& ax, unsigned int* __restrict__ hb, int l15, int g4,
    const bf16x8* whh_hi, const bf16x8* whh_lo,
    const bf16x8* wih_hi, const bf16x8* wih_lo,
    const f32x4* bvec, float* cst, float* hv)
{
    const int c0 = g4 * 2;
    const int swz = (l15 & 3) << 1;
    uint4 v0 = *(const uint4*)(hb + l15 * 32 + ((c0 ^ swz) << 2));
    uint4 v1 = *(const uint4*)(hb + l15 * 32 + (((c0 + 1) ^ swz) << 2));
    union { unsigned int u[4]; bf16x8 v; } ahi, alo;
    ahi.u[0] = __builtin_amdgcn_perm(v0.y, v0.x, 0x05040100u);
    ahi.u[1] = __builtin_amdgcn_perm(v0.w, v0.z, 0x05040100u);
    ahi.u[2] = __builtin_amdgcn_perm(v1.y, v1.x, 0x05040100u);
    ahi.u[3] = __builtin_amdgcn_perm(v1.w, v1.z, 0x05040100u);
    alo.u[0] = __builtin_amdgcn_perm(v0.y, v0.x, 0x07060302u);
    alo.u[1] = __builtin_amdgcn_perm(v0.w, v0.z, 0x07060302u);
    alo.u[2] = __builtin_amdgcn_perm(v1.y, v1.x, 0x07060302u);
    alo.u[3] = __builtin_amdgcn_perm(v1.w, v1.z, 0x07060302u);

    f32x4 z[8];
    #pragma unroll
    for (int f = 0; f < 8; ++f) {
        f32x4 a = __builtin_amdgcn_mfma_f32_16x16x32_bf16(ax,    wih_hi[f], bvec[f], 0, 0, 0);
        a = __builtin_amdgcn_mfma_f32_16x16x32_bf16(ax,    wih_lo[f], a, 0, 0, 0);
        a = __builtin_amdgcn_mfma_f32_16x16x32_bf16(ahi.v, whh_hi[f], a, 0, 0, 0);
        a = __builtin_amdgcn_mfma_f32_16x16x32_bf16(ahi.v, whh_lo[f], a, 0, 0, 0);
        a = __builtin_amdgcn_mfma_f32_16x16x32_bf16(alo.v, whh_hi[f], a, 0, 0, 0);
        z[f] = a;
    }

    #pragma unroll
    for (int Hh = 0; Hh < 2; ++Hh) {
        #pragma unroll
        for (int r = 0; r < 4; ++r) {
            const int idx = Hh * 4 + r;
            float zi = z[0 + Hh][r], zf = z[2 + Hh][r];
            float zg = z[4 + Hh][r], zo = z[6 + Hh][r];
            float cn = fmaf(sigm(zf), cst[idx], sigm(zi) * tanh_fast(zg));
            cst[idx] = cn;
            float h = sigm(zo) * tanh_fast(cn);
            hv[idx] = h;
            __bf16 hh_ = (__bf16)h;
            __bf16 hl_ = (__bf16)(h - (float)hh_);
            unsigned int pk = (unsigned int)__builtin_bit_cast(unsigned short, hh_)
                            | ((unsigned int)__builtin_bit_cast(unsigned short, hl_) << 16);
            const int mm = g4 * 4 + r;
            const int jw = Hh * 16 + l15;
            hb[mm * 32 + (((jw >> 2) ^ ((mm & 3) << 1)) << 2) + (jw & 3)] = pk;
        }
    }
}

__global__ __launch_bounds__(256, 1) void lstm_mfma_kernel(
    const float* __restrict__ anchor, const float* __restrict__ pos,
    const float* __restrict__ neg, const float* __restrict__ Wih,
    const float* __restrict__ Whh, const float* __restrict__ bias,
    float* __restrict__ hn)
{
    __shared__ unsigned int Hbuf[4][512];   // wave-private [16 m][32 j] hi|lo
    const int tid  = threadIdx.x;
    const int w    = tid >> 6;
    const int lane = tid & 63;
    const int l15  = lane & 15;
    const int g4   = lane >> 4;
    unsigned int* hb = Hbuf[w];

    // zero own region (wave-private; DS FIFO keeps it ordered for this wave)
    #pragma unroll
    for (int i = 0; i < 8; ++i) hb[lane + i * 64] = 0u;

    // B-fragments + bias for all 8 tiles
    bf16x8 whh_hi[8], whh_lo[8], wih_hi[8], wih_lo[8];
    f32x4 bvec[8];
    #pragma unroll
    for (int f = 0; f < 8; ++f) {
        const int G = f >> 1, Hh = f & 1;
        const int c = G * 32 + Hh * 16 + l15;
        const float bq = bias[c];
        bvec[f][0] = bq; bvec[f][1] = bq; bvec[f][2] = bq; bvec[f][3] = bq;
        const float* wr = Whh + c * 32 + g4 * 8;
        #pragma unroll
        for (int i = 0; i < 8; ++i) {
            float wv = wr[i];
            __bf16 hi = (__bf16)wv;
            whh_hi[f][i] = hi;
            whh_lo[f][i] = (__bf16)(wv - (float)hi);
        }
        if (g4 < 2) {
            const float* wr2 = Wih + c * 16 + g4 * 8;
            #pragma unroll
            for (int i = 0; i < 8; ++i) {
                float wv = wr2[i];
                __bf16 hi = (__bf16)wv;
                wih_hi[f][i] = hi;
                wih_lo[f][i] = (__bf16)(wv - (float)hi);
            }
        } else {
            #pragma unroll
            for (int i = 0; i < 8; ++i) {
                wih_hi[f][i] = (__bf16)0.f; wih_lo[f][i] = (__bf16)0.f;
            }
        }
    }

    // x source: seq s = blk*64 + w*16 + l15, features f = 8*g4+i (g4<2 only)
    const int s = blockIdx.x * 64 + w * 16 + l15;
    const float* xbase; int sl;
    if (s < 2048)      { xbase = anchor; sl = s; }
    else if (s < 4096) { xbase = pos;    sl = s - 2048; }
    else               { xbase = neg;    sl = s - 4096; }
    const bool xact = (g4 < 2);
    const float* xp = xbase + (sl >> 7) * 131072 + (sl & 127) * 16 + (xact ? g4 * 8 : 0);

    const float4 z4 = make_float4(0.f, 0.f, 0.f, 0.f);
    float4 xaA = z4, xbA = z4, xaB = z4, xbB = z4;
    if (xact) {
        xaA = *(const float4*)(xp);        xbA = *(const float4*)(xp + 4);
        xaB = *(const float4*)(xp + 2048); xbB = *(const float4*)(xp + 2052);
    }

    float cst[8] = {0.f,0.f,0.f,0.f,0.f,0.f,0.f,0.f};
    float hv[8]  = {0.f,0.f,0.f,0.f,0.f,0.f,0.f,0.f};

    for (int t = 0; t < 64; t += 2) {
        bf16x8 ax;
        ax[0]=(__bf16)xaA.x; ax[1]=(__bf16)xaA.y; ax[2]=(__bf16)xaA.z; ax[3]=(__bf16)xaA.w;
        ax[4]=(__bf16)xbA.x; ax[5]=(__bf16)xbA.y; ax[6]=(__bf16)xbA.z; ax[7]=(__bf16)xbA.w;
        if (xact && t + 2 < 64) {
            const float* p = xp + (t + 2) * 2048;
            xaA = *(const float4*)(p); xbA = *(const float4*)(p + 4);
        }
        lstm_step(ax, hb, l15, g4, whh_hi, whh_lo, wih_hi, wih_lo, bvec, cst, hv);

        ax[0]=(__bf16)xaB.x; ax[1]=(__bf16)xaB.y; ax[2]=(__bf16)xaB.z; ax[3]=(__bf16)xaB.w;
        ax[4]=(__bf16)xbB.x; ax[5]=(__bf16)xbB.y; ax[6]=(__bf16)xbB.z; ax[7]=(__bf16)xbB.w;
        if (xact && t + 3 < 64) {
            const float* p = xp + (t + 3) * 2048;
            xaB = *(const float4*)(p); xbB = *(const float4*)(p + 4);
        }
        lstm_step(ax, hb, l15, g4, whh_hi, whh_lo, wih_hi, wih_lo, bvec, cst, hv);
    }

    // epilogue: hn[seq][unit]
    const int seq0 = blockIdx.x * 64 + w * 16;
    #pragma unroll
    for (int Hh = 0; Hh < 2; ++Hh) {
        #pragma unroll
        for (int r = 0; r < 4; ++r) {
            hn[(seq0 + g4 * 4 + r) * 32 + Hh * 16 + l15] = hv[Hh * 4 + r];
        }
    }
}

// ---------------------------------------------------------------------------
// GATv2 layer 1, single-pass fused softmax+PV, 512 threads:
// thread = (d = tid>>2, s-quarter of 32); shfl_xor(1,2) reduces; only the
// sq==0 lane of each quad stores (static acc indexing, rule #20).
// lrelu split: a.lrelu(e) = 0.6 a.e + 0.4 a.|e|. Logits structurally bounded
// (|h|<1, W~1/sqrt(32)) -> exp without max-shift is fp32-safe.
// ---------------------------------------------------------------------------
__global__ __launch_bounds__(512) void gat1_kernel(
    const float* __restrict__ hn, const float* __restrict__ W1s,
    const float* __restrict__ W1d, const float* __restrict__ a1,
    const float* __restrict__ b1, float* __restrict__ h1heads)
{
    const int g = blockIdx.x >> 3, hd = blockIdx.x & 7;
    __shared__ float FS[128][36];
    __shared__ float FD[128][36];
    __shared__ float AVr[32];
    __shared__ float As06[128];
    __shared__ float Ad06[128];
    const int tid = threadIdx.x;

    if (tid < 32) AVr[tid] = a1[hd * 32 + tid];

    // Phase A: fs = h@Ws, fd = h@Wd. thread = (o, 8-row slab).
    {
        const int o = tid & 31, nb = tid >> 5;      // nb in 0..15
        float wcs[32], wcd[32];
        const float* wsp = W1s + hd * 1024 + o;
        const float* wdp = W1d + hd * 1024 + o;
        #pragma unroll
        for (int k = 0; k < 32; ++k) { wcs[k] = wsp[k * 32]; wcd[k] = wdp[k * 32]; }
        const float* hp = hn + g * 4096 + nb * 256;
        #pragma unroll 1
        for (int n = 0; n < 8; ++n) {
            float a0 = 0.f, a1_ = 0.f, b0 = 0.f, b1_ = 0.f;
            #pragma unroll
            for (int k0 = 0; k0 < 32; k0 += 4) {
                float4 hv = *(const float4*)(hp + n * 32 + k0);
                a0 = fmaf(hv.x, wcs[k0+0], a0); b0 = fmaf(hv.x, wcd[k0+0], b0);
                a1_ = fmaf(hv.y, wcs[k0+1], a1_); b1_ = fmaf(hv.y, wcd[k0+1], b1_);
                a0 = fmaf(hv.z, wcs[k0+2], a0); b0 = fmaf(hv.z, wcd[k0+2], b0);
                a1_ = fmaf(hv.w, wcs[k0+3], a1_); b1_ = fmaf(hv.w, wcd[k0+3], b1_);
            }
            FS[nb * 8 + n][o] = a0 + a1_;
            FD[nb * 8 + n][o] = b0 + b1_;
        }
    }
    __syncthreads();

    if (tid < 128) {
        float ss = 0.f, sd = 0.f;
        #pragma unroll
        for (int oo = 0; oo < 32; ++oo) {
            int o = (oo + tid) & 31;
            float a = AVr[o];
            ss = fmaf(a, FS[tid][o], ss);
            sd = fmaf(a, FD[tid][o], sd);
        }
        As06[tid] = 0.6f * ss;
        Ad06[tid] = 0.6f * sd;
    }
    __syncthreads();

    const int d = tid >> 2, sq = tid & 3, sbase = sq << 5;
    float fdr[32], avs[32];
    #pragma unroll
    for (int c = 0; c < 8; ++c) {
        float4 v = *(const float4*)&FD[d][c * 4];
        fdr[c*4+0] = v.x; fdr[c*4+1] = v.y; fdr[c*4+2] = v.z; fdr[c*4+3] = v.w;
        float4 w = *(const float4*)&AVr[c * 4];
        avs[c*4+0] = 0.4f * w.x; avs[c*4+1] = 0.4f * w.y;
        avs[c*4+2] = 0.4f * w.z; avs[c*4+3] = 0.4f * w.w;
    }
    const float adc = Ad06[d];

    float Z = 0.f;
    float acc[32];
    #pragma unroll
    for (int o = 0; o < 32; ++o) acc[o] = 0.f;
    #pragma unroll 1
    for (int si = 0; si < 32; ++si) {
        const int s = sbase + si;
        float4 fa[8];
        #pragma unroll
        for (int c = 0; c < 8; ++c) fa[c] = *(const float4*)&FS[s][c * 4];
        float c0 = 0.f, c1 = 0.f, c2 = 0.f, c3 = 0.f;
        #pragma unroll
        for (int c = 0; c < 8; ++c) {
            float e0 = fdr[c*4+0] + fa[c].x; c0 = fmaf(avs[c*4+0], __builtin_fabsf(e0), c0);
            float e1 = fdr[c*4+1] + fa[c].y; c1 = fmaf(avs[c*4+1], __builtin_fabsf(e1), c1);
            float e2 = fdr[c*4+2] + fa[c].z; c2 = fmaf(avs[c*4+2], __builtin_fabsf(e2), c2);
            float e3 = fdr[c*4+3] + fa[c].w; c3 = fmaf(avs[c*4+3], __builtin_fabsf(e3), c3);
        }
        float v = adc + As06[s] + ((c0 + c1) + (c2 + c3));
        float e = (s == d) ? 0.f : __expf(v);
        Z += e;
        #pragma unroll
        for (int c = 0; c < 8; ++c) {
            acc[c*4+0] = fmaf(e, fa[c].x, acc[c*4+0]);
            acc[c*4+1] = fmaf(e, fa[c].y, acc[c*4+1]);
            acc[c*4+2] = fmaf(e, fa[c].z, acc[c*4+2]);
            acc[c*4+3] = fmaf(e, fa[c].w, acc[c*4+3]);
        }
    }
    Z += __shfl_xor(Z, 1); Z += __shfl_xor(Z, 2);
    const float rz = fast_rcp(Z);
    #pragma unroll
    for (int o = 0; o < 32; ++o) {
        acc[o] += __shfl_xor(acc[o], 1);
        acc[o] += __shfl_xor(acc[o], 2);
    }

    if (sq == 0) {
        float* dst = h1heads + ((size_t)((g * 8 + hd) * 128 + d)) * 32;
        const float* bp = b1 + hd * 32;
        #pragma unroll
        for (int c = 0; c < 8; ++c) {
            float4 v;
            v.x = fmaf(acc[c*4+0], rz, bp[c*4+0]);
            v.y = fmaf(acc[c*4+1], rz, bp[c*4+1]);
            v.z = fmaf(acc[c*4+2], rz, bp[c*4+2]);
            v.w = fmaf(acc[c*4+3], rz, bp[c*4+3]);
            *(float4*)(dst + c * 4) = v;
        }
    }
}

// ---------------------------------------------------------------------------
// GATv2 layer 2, same 512-thread single-pass structure: one block per graph.
// ---------------------------------------------------------------------------
__global__ __launch_bounds__(512) void gat2_kernel(
    const float* __restrict__ h1heads, const float* __restrict__ W2s,
    const float* __restrict__ W2d, const float* __restrict__ a2,
    const float* __restrict__ b2, float* __restrict__ pooled)
{
    const int g = blockIdx.x;
    __shared__ float HS[128][36];
    __shared__ float FS[128][36];
    __shared__ float FD[128][36];     // reused as OUT after the fused pass
    __shared__ float AVr[32];
    __shared__ float As06[128];
    __shared__ float Ad06[128];
    const int tid = threadIdx.x;

    if (tid < 32) AVr[tid] = a2[tid];

    // stage: h1 = mean over 8 heads
    {
        #pragma unroll
        for (int i = 0; i < 2; ++i) {
            int idx4 = i * 512 + tid;
            float sx = 0.f, sy = 0.f, sz = 0.f, sw = 0.f;
            #pragma unroll
            for (int hdd = 0; hdd < 8; ++hdd) {
                const float4* src = (const float4*)(h1heads + (size_t)(g * 8 + hdd) * 4096);
                float4 v = src[idx4];
                sx += v.x; sy += v.y; sz += v.z; sw += v.w;
            }
            int n = idx4 >> 3, k0 = (idx4 & 7) * 4;
            float4 r; r.x = sx * 0.125f; r.y = sy * 0.125f; r.z = sz * 0.125f; r.w = sw * 0.125f;
            *(float4*)&HS[n][k0] = r;
        }
    }
    __syncthreads();

    // Phase A
    {
        const int o = tid & 31, nb = tid >> 5;
        float wcs[32], wcd[32];
        const float* wsp = W2s + o;
        const float* wdp = W2d + o;
        #pragma unroll
        for (int k = 0; k < 32; ++k) { wcs[k] = wsp[k * 32]; wcd[k] = wdp[k * 32]; }
        #pragma unroll 1
        for (int n = nb * 8; n < nb * 8 + 8; ++n) {
            float a0 = 0.f, a1_ = 0.f, b0 = 0.f, b1_ = 0.f;
            #pragma unroll
            for (int k0 = 0; k0 < 32; k0 += 4) {
                const float4 hv = *(const float4*)&HS[n][k0];
                a0 = fmaf(hv.x, wcs[k0+0], a0); b0 = fmaf(hv.x, wcd[k0+0], b0);
                a1_ = fmaf(hv.y, wcs[k0+1], a1_); b1_ = fmaf(hv.y, wcd[k0+1], b1_);
                a0 = fmaf(hv.z, wcs[k0+2], a0); b0 = fmaf(hv.z, wcd[k0+2], b0);
                a1_ = fmaf(hv.w, wcs[k0+3], a1_); b1_ = fmaf(hv.w, wcd[k0+3], b1_);
            }
            FS[n][o] = a0 + a1_;
            FD[n][o] = b0 + b1_;
        }
    }
    __syncthreads();

    if (tid < 128) {
        float ss = 0.f, sd = 0.f;
        #pragma unroll
        for (int oo = 0; oo < 32; ++oo) {
            int o = (oo + tid) & 31;
            float a = AVr[o];
            ss = fmaf(a, FS[tid][o], ss);
            sd = fmaf(a, FD[tid][o], sd);
        }
        As06[tid] = 0.6f * ss;
        Ad06[tid] = 0.6f * sd;
    }
    __syncthreads();

    const int d = tid >> 2, sq = tid & 3, sbase = sq << 5;
    float fdr[32], avs[32];
    #pragma unroll
    for (int c = 0; c < 8; ++c) {
        float4 v = *(const float4*)&FD[d][c * 4];
        fdr[c*4+0] = v.x; fdr[c*4+1] = v.y; fdr[c*4+2] = v.z; fdr[c*4+3] = v.w;
        float4 w = *(const float4*)&AVr[c * 4];
        avs[c*4+0] = 0.4f * w.x; avs[c*4+1] = 0.4f * w.y;
        avs[c*4+2] = 0.4f * w.z; avs[c*4+3] = 0.4f * w.w;
    }
    const float adc = Ad06[d];

    float Z = 0.f;
    float acc[32];
    #pragma unroll
    for (int o = 0; o < 32; ++o) acc[o] = 0.f;
    #pragma unroll 1
    for (int si = 0; si < 32; ++si) {
        const int s = sbase + si;
        float4 fa[8];
        #pragma unroll
        for (int c = 0; c < 8; ++c) fa[c] = *(const float4*)&FS[s][c * 4];
        float c0 = 0.f, c1 = 0.f, c2 = 0.f, c3 = 0.f;
        #pragma unroll
        for (int c = 0; c < 8; ++c) {
            float e0 = fdr[c*4+0] + fa[c].x; c0 = fmaf(avs[c*4+0], __builtin_fabsf(e0), c0);
            float e1 = fdr[c*4+1] + fa[c].y; c1 = fmaf(avs[c*4+1], __builtin_fabsf(e1), c1);
            float e2 = fdr[c*4+2] + fa[c].z; c2 = fmaf(avs[c*4+2], __builtin_fabsf(e2), c2);
            float e3 = fdr[c*4+3] + fa[c].w; c3 = fmaf(avs[c*4+3], __builtin_fabsf(e3), c3);
        }
        float v = adc + As06[s] + ((c0 + c1) + (c2 + c3));
        float e = (s == d) ? 0.f : __expf(v);
        Z += e;
        #pragma unroll
        for (int c = 0; c < 8; ++c) {
            acc[c*4+0] = fmaf(e, fa[c].x, acc[c*4+0]);
            acc[c*4+1] = fmaf(e, fa[c].y, acc[c*4+1]);
            acc[c*4+2] = fmaf(e, fa[c].z, acc[c*4+2]);
            acc[c*4+3] = fmaf(e, fa[c].w, acc[c*4+3]);
        }
    }
    Z += __shfl_xor(Z, 1); Z += __shfl_xor(Z, 2);
    const float rz = fast_rcp(Z);
    #pragma unroll
    for (int o = 0; o < 32; ++o) {
        acc[o] += __shfl_xor(acc[o], 1);
        acc[o] += __shfl_xor(acc[o], 2);
    }

    __syncthreads();     // all FD reads done -> safe to reuse FD as OUT
    if (sq == 0) {
        #pragma unroll
        for (int c = 0; c < 8; ++c) {
            float4 v;
            v.x = acc[c*4+0] * rz; v.y = acc[c*4+1] * rz;
            v.z = acc[c*4+2] * rz; v.w = acc[c*4+3] * rz;
            *(float4*)&FD[d][c * 4] = v;
        }
    }
    __syncthreads();

    // pooled[g][o] = mean_n OUT[n][o] + b2[o]
    if (tid < 32) {
        float sp = 0.f;
        #pragma unroll 1
        for (int n = 0; n < 128; ++n) sp += FD[n][tid];
        pooled[g * 32 + tid] = fmaf(sp, 1.f / 128.f, b2[tid]);
    }
}

// ---------------------------------------------------------------------------
// Final: cosine sims, contrastive loss, output assembly.
// ---------------------------------------------------------------------------
__global__ void final_kernel(const float* __restrict__ pooled,
                             const float* __restrict__ hideout,
                             const float* __restrict__ timestep,
                             float* __restrict__ out)
{
    const int b = threadIdx.x;
    __shared__ float lossArr[16];
    if (b < 16) {
        const float* A  = pooled + b * 32;
        const float* Pv = pooled + (16 + b) * 32;
        float av[32];
        float na = 0.f;
        #pragma unroll
        for (int i = 0; i < 32; ++i) { av[i] = A[i]; na += av[i] * av[i]; }
        float npv = 0.f, dp = 0.f;
        #pragma unroll
        for (int i = 0; i < 32; ++i) { float p = Pv[i]; npv += p * p; dp += av[i] * p; }
        const float eps = 1e-6f;
        const float ia = 1.f / fmaxf(sqrtf(na), eps);
        const float sp = dp * ia / fmaxf(sqrtf(npv), eps);
        float sn[4];
        #pragma unroll
        for (int k = 0; k < 4; ++k) {
            const float* Nv = pooled + (32 + b * 4 + k) * 32;
            float nn = 0.f, dn = 0.f;
            #pragma unroll
            for (int i = 0; i < 32; ++i) { float q = Nv[i]; nn += q * q; dn += av[i] * q; }
            sn[k] = dn * ia / fmaxf(sqrtf(nn), eps);
        }
        float m = sp;
        #pragma unroll
        for (int k = 0; k < 4; ++k) m = fmaxf(m, sn[k]);
        float Z = expf(sp - m);
        #pragma unroll
        for (int k = 0; k < 4; ++k) Z += expf(sn[k] - m);
        lossArr[b] = logf(Z) + m - sp;
        float* r = out + b * 35;
        #pragma unroll
        for (int i = 0; i < 32; ++i) r[i] = av[i];
        r[32] = hideout[b * 2];
        r[33] = hideout[b * 2 + 1];
        r[34] = timestep[b];
    }
    __syncthreads();
    if (b == 0) {
        float s = 0.f;
        #pragma unroll
        for (int i = 0; i < 16; ++i) s += lossArr[i];
        out[560] = s * (1.f / 16.f);
    }
}

extern "C" void kernel_launch(void* const* d_in, const int* in_sizes, int n_in,
                              void* d_out, int out_size, void* d_ws, size_t ws_size,
                              hipStream_t stream) {
    const float* anchor   = (const float*)d_in[0];
    const float* pos      = (const float*)d_in[1];
    const float* neg      = (const float*)d_in[2];
    const float* hideout  = (const float*)d_in[3];
    const float* timestep = (const float*)d_in[4];
    const float* Wih      = (const float*)d_in[5];
    const float* Whh      = (const float*)d_in[6];
    const float* b_lstm   = (const float*)d_in[7];
    const float* W1s      = (const float*)d_in[8];
    const float* W1d      = (const float*)d_in[9];
    const float* a1       = (const float*)d_in[10];
    const float* b1       = (const float*)d_in[11];
    const float* W2s      = (const float*)d_in[12];
    const float* W2d      = (const float*)d_in[13];
    const float* a2       = (const float*)d_in[14];
    const float* b2       = (const float*)d_in[15];
    float* out = (float*)d_out;

    char* ws = (char*)d_ws;
    float* hn      = (float*)(ws);                       // 12288*32*4   = 1,572,864 B
    float* h1heads = (float*)(ws + 1605632);             // 96*8*128*32*4 = 12,582,912 B
    float* pooled  = (float*)(ws + 14188544);            // 96*32*4      = 12,288 B

    hipLaunchKernelGGL(lstm_mfma_kernel, dim3(192), dim3(256), 0, stream,
                       anchor, pos, neg, Wih, Whh, b_lstm, hn);
    hipLaunchKernelGGL(gat1_kernel,  dim3(768),  dim3(512), 0, stream,
                       hn, W1s, W1d, a1, b1, h1heads);
    hipLaunchKernelGGL(gat2_kernel,  dim3(96),   dim3(512), 0, stream,
                       h1heads, W2s, W2d, a2, b2, pooled);
    hipLaunchKernelGGL(final_kernel, dim3(1),    dim3(64),  0, stream,
                       pooled, hideout, timestep, out);
}

// Round 7
// 177.721 us; speedup vs baseline: 4.8792x; 1.0813x over previous
//
#include <hip/hip_runtime.h>
#include <math.h>

// Problem constants: B=16, K=4, T=64, N=128, F=16, H=32, NH=8, GH=32
// Sequences: 12288 = 2048 anchor + 2048 pos + 8192 neg. Graphs: 96 = 16+16+64.

typedef __bf16 bf16x8 __attribute__((ext_vector_type(8)));
typedef float  f32x4  __attribute__((ext_vector_type(4)));
typedef unsigned int u32x4 __attribute__((ext_vector_type(4)));

__device__ __forceinline__ float fast_rcp(float x) { return __builtin_amdgcn_rcpf(x); }
__device__ __forceinline__ float sigm(float x)     { return fast_rcp(1.f + __expf(-x)); }
__device__ __forceinline__ float tanh_fast(float x){ return fmaf(2.f, fast_rcp(1.f + __expf(-2.f * x)), -1.f); }

// Opaque identity: value becomes an asm output -> compiler cannot
// rematerialize it by re-loading from global inside the loop.
#define KEEP4(x) asm volatile("" : "+v"(x))

// ---------------------------------------------------------------------------
// LSTM via MFMA, barrier-free single-wave recurrence, weights PINNED in VGPRs.
// Wave owns 16 seqs and all 128 gate cols (8 tiles of 16). Per-step h
// transpose through wave-private LDS (per-wave DS FIFO, no __syncthreads).
// 4 MFMAs/tile: ax*wih_hi + ahi*whh_hi + ahi*whh_lo + alo*whh_hi
// (wih_lo dropped: x is bf16-quantized anyway; error ~4e-3 << 4.7e-2 thr).
// Bias added as scalar in activation phase (saves 24 VGPRs vs bvec).
// ---------------------------------------------------------------------------
__global__ __launch_bounds__(256, 1) void lstm_mfma_kernel(
    const float* __restrict__ anchor, const float* __restrict__ pos,
    const float* __restrict__ neg, const float* __restrict__ Wih,
    const float* __restrict__ Whh, const float* __restrict__ bias,
    float* __restrict__ hn)
{
    __shared__ unsigned int Hbuf[4][512];   // wave-private [16 m][32 j] hi|lo
    const int tid  = threadIdx.x;
    const int w    = tid >> 6;
    const int lane = tid & 63;
    const int l15  = lane & 15;
    const int g4   = lane >> 4;
    unsigned int* hb = Hbuf[w];

    #pragma unroll
    for (int i = 0; i < 8; ++i) hb[lane + i * 64] = 0u;

    // B-fragments (as u32x4 so they can be asm-pinned) + scalar bias
    u32x4 whhH[8], whhL[8], wihH[8];
    float bq[8];
    #pragma unroll
    for (int f = 0; f < 8; ++f) {
        const int G = f >> 1, Hh = f & 1;
        const int c = G * 32 + Hh * 16 + l15;
        bq[f] = bias[c];
        union { u32x4 u; bf16x8 v; } th, tl, ti;
        const float* wr = Whh + c * 32 + g4 * 8;
        #pragma unroll
        for (int i = 0; i < 8; ++i) {
            float wv = wr[i];
            __bf16 hi = (__bf16)wv;
            th.v[i] = hi;
            tl.v[i] = (__bf16)(wv - (float)hi);
        }
        if (g4 < 2) {
            const float* wr2 = Wih + c * 16 + g4 * 8;
            #pragma unroll
            for (int i = 0; i < 8; ++i) ti.v[i] = (__bf16)wr2[i];
        } else {
            #pragma unroll
            for (int i = 0; i < 8; ++i) ti.v[i] = (__bf16)0.f;
        }
        whhH[f] = th.u; whhL[f] = tl.u; wihH[f] = ti.u;
    }
    // Pin all fragments in registers (cannot be rematerialized past this)
    #pragma unroll
    for (int f = 0; f < 8; ++f) { KEEP4(whhH[f]); KEEP4(whhL[f]); KEEP4(wihH[f]); }

    // x source: seq s = blk*64 + w*16 + l15, features 8*g4+i (g4<2 only)
    const int s = blockIdx.x * 64 + w * 16 + l15;
    const float* xbase; int sl;
    if (s < 2048)      { xbase = anchor; sl = s; }
    else if (s < 4096) { xbase = pos;    sl = s - 2048; }
    else               { xbase = neg;    sl = s - 4096; }
    const bool xact = (g4 < 2);
    const float* xp = xbase + (sl >> 7) * 131072 + (sl & 127) * 16 + (xact ? g4 * 8 : 0);

    const float4 z4 = make_float4(0.f, 0.f, 0.f, 0.f);
    float4 xaA = z4, xbA = z4, xaB = z4, xbB = z4;
    if (xact) {
        xaA = *(const float4*)(xp);        xbA = *(const float4*)(xp + 4);
        xaB = *(const float4*)(xp + 2048); xbB = *(const float4*)(xp + 2052);
    }

    float cst[8] = {0.f,0.f,0.f,0.f,0.f,0.f,0.f,0.f};
    float hv[8]  = {0.f,0.f,0.f,0.f,0.f,0.f,0.f,0.f};

    #define LSTM_STEP(XA, XB)                                                          \
    {                                                                                  \
        bf16x8 ax;                                                                     \
        ax[0]=(__bf16)XA.x; ax[1]=(__bf16)XA.y; ax[2]=(__bf16)XA.z; ax[3]=(__bf16)XA.w;\
        ax[4]=(__bf16)XB.x; ax[5]=(__bf16)XB.y; ax[6]=(__bf16)XB.z; ax[7]=(__bf16)XB.w;\
        const int c0 = g4 * 2;                                                         \
        const int swz = (l15 & 3) << 1;                                                \
        uint4 v0 = *(const uint4*)(hb + l15 * 32 + ((c0 ^ swz) << 2));                 \
        uint4 v1 = *(const uint4*)(hb + l15 * 32 + (((c0 + 1) ^ swz) << 2));           \
        union { unsigned int u[4]; bf16x8 v; } ahi, alo;                               \
        ahi.u[0] = __builtin_amdgcn_perm(v0.y, v0.x, 0x05040100u);                     \
        ahi.u[1] = __builtin_amdgcn_perm(v0.w, v0.z, 0x05040100u);                     \
        ahi.u[2] = __builtin_amdgcn_perm(v1.y, v1.x, 0x05040100u);                     \
        ahi.u[3] = __builtin_amdgcn_perm(v1.w, v1.z, 0x05040100u);                     \
        alo.u[0] = __builtin_amdgcn_perm(v0.y, v0.x, 0x07060302u);                     \
        alo.u[1] = __builtin_amdgcn_perm(v0.w, v0.z, 0x07060302u);                     \
        alo.u[2] = __builtin_amdgcn_perm(v1.y, v1.x, 0x07060302u);                     \
        alo.u[3] = __builtin_amdgcn_perm(v1.w, v1.z, 0x07060302u);                     \
        f32x4 z[8];                                                                    \
        _Pragma("unroll")                                                              \
        for (int f = 0; f < 8; ++f) {                                                  \
            f32x4 a = __builtin_amdgcn_mfma_f32_16x16x32_bf16(                         \
                ax, __builtin_bit_cast(bf16x8, wihH[f]), (f32x4)(0.f), 0, 0, 0);       \
            a = __builtin_amdgcn_mfma_f32_16x16x32_bf16(                               \
                ahi.v, __builtin_bit_cast(bf16x8, whhH[f]), a, 0, 0, 0);               \
            a = __builtin_amdgcn_mfma_f32_16x16x32_bf16(                               \
                ahi.v, __builtin_bit_cast(bf16x8, whhL[f]), a, 0, 0, 0);               \
            a = __builtin_amdgcn_mfma_f32_16x16x32_bf16(                               \
                alo.v, __builtin_bit_cast(bf16x8, whhH[f]), a, 0, 0, 0);               \
            z[f] = a;                                                                  \
        }                                                                              \
        _Pragma("unroll")                                                              \
        for (int Hh = 0; Hh < 2; ++Hh) {                                               \
            _Pragma("unroll")                                                          \
            for (int r = 0; r < 4; ++r) {                                              \
                const int idx = Hh * 4 + r;                                            \
                float zi = z[0 + Hh][r] + bq[0 + Hh];                                  \
                float zf = z[2 + Hh][r] + bq[2 + Hh];                                  \
                float zg = z[4 + Hh][r] + bq[4 + Hh];                                  \
                float zo = z[6 + Hh][r] + bq[6 + Hh];                                  \
                float cn = fmaf(sigm(zf), cst[idx], sigm(zi) * tanh_fast(zg));         \
                cst[idx] = cn;                                                         \
                float h = sigm(zo) * tanh_fast(cn);                                    \
                hv[idx] = h;                                                           \
                __bf16 hh_ = (__bf16)h;                                                \
                __bf16 hl_ = (__bf16)(h - (float)hh_);                                 \
                unsigned int pk = (unsigned int)__builtin_bit_cast(unsigned short, hh_)\
                                | ((unsigned int)__builtin_bit_cast(unsigned short, hl_) << 16); \
                const int mm = g4 * 4 + r;                                             \
                const int jw = Hh * 16 + l15;                                          \
                hb[mm * 32 + (((jw >> 2) ^ ((mm & 3) << 1)) << 2) + (jw & 3)] = pk;    \
            }                                                                          \
        }                                                                              \
    }

    for (int t = 0; t < 64; t += 2) {
        float4 cA1 = xaA, cA2 = xbA;
        if (xact && t + 2 < 64) {
            const float* p = xp + (t + 2) * 2048;
            xaA = *(const float4*)(p); xbA = *(const float4*)(p + 4);
        }
        LSTM_STEP(cA1, cA2);

        float4 cB1 = xaB, cB2 = xbB;
        if (xact && t + 3 < 64) {
            const float* p = xp + (t + 3) * 2048;
            xaB = *(const float4*)(p); xbB = *(const float4*)(p + 4);
        }
        LSTM_STEP(cB1, cB2);
    }
    #undef LSTM_STEP

    const int seq0 = blockIdx.x * 64 + w * 16;
    #pragma unroll
    for (int Hh = 0; Hh < 2; ++Hh) {
        #pragma unroll
        for (int r = 0; r < 4; ++r) {
            hn[(seq0 + g4 * 4 + r) * 32 + Hh * 16 + l15] = hv[Hh * 4 + r];
        }
    }
}

// ---------------------------------------------------------------------------
// GATv2 layer 1, single-pass fused softmax+PV, 256 threads (R5 config:
// thread = (d, s-half); 2-way LDS row alias is free, 4-way at 512thr is not).
// lrelu split: a.lrelu(e) = 0.6 a.e + 0.4 a.|e|; exp without max-shift is
// fp32-safe (logits structurally bounded).
// ---------------------------------------------------------------------------
__global__ __launch_bounds__(256) void gat1_kernel(
    const float* __restrict__ hn, const float* __restrict__ W1s,
    const float* __restrict__ W1d, const float* __restrict__ a1,
    const float* __restrict__ b1, float* __restrict__ h1heads)
{
    const int g = blockIdx.x >> 3, hd = blockIdx.x & 7;
    __shared__ float FS[128][36];
    __shared__ float FD[128][36];
    __shared__ float AVr[32];
    __shared__ float As06[128];
    __shared__ float Ad06[128];
    const int tid = threadIdx.x;

    if (tid < 32) AVr[tid] = a1[hd * 32 + tid];

    // Phase A: fs = h@Ws, fd = h@Wd. thread = (o, 16-row slab).
    {
        const int o = tid & 31, nb = tid >> 5;
        float wcs[32], wcd[32];
        const float* wsp = W1s + hd * 1024 + o;
        const float* wdp = W1d + hd * 1024 + o;
        #pragma unroll
        for (int k = 0; k < 32; ++k) { wcs[k] = wsp[k * 32]; wcd[k] = wdp[k * 32]; }
        const float* hp = hn + g * 4096 + nb * 512;
        #pragma unroll 1
        for (int n = 0; n < 16; ++n) {
            float a0 = 0.f, a1_ = 0.f, b0 = 0.f, b1_ = 0.f;
            #pragma unroll
            for (int k0 = 0; k0 < 32; k0 += 4) {
                float4 hv = *(const float4*)(hp + n * 32 + k0);
                a0 = fmaf(hv.x, wcs[k0+0], a0); b0 = fmaf(hv.x, wcd[k0+0], b0);
                a1_ = fmaf(hv.y, wcs[k0+1], a1_); b1_ = fmaf(hv.y, wcd[k0+1], b1_);
                a0 = fmaf(hv.z, wcs[k0+2], a0); b0 = fmaf(hv.z, wcd[k0+2], b0);
                a1_ = fmaf(hv.w, wcs[k0+3], a1_); b1_ = fmaf(hv.w, wcd[k0+3], b1_);
            }
            FS[nb * 16 + n][o] = a0 + a1_;
            FD[nb * 16 + n][o] = b0 + b1_;
        }
    }
    __syncthreads();

    if (tid < 128) {
        float ss = 0.f, sd = 0.f;
        #pragma unroll
        for (int oo = 0; oo < 32; ++oo) {
            int o = (oo + tid) & 31;
            float a = AVr[o];
            ss = fmaf(a, FS[tid][o], ss);
            sd = fmaf(a, FD[tid][o], sd);
        }
        As06[tid] = 0.6f * ss;
        Ad06[tid] = 0.6f * sd;
    }
    __syncthreads();

    const int d = tid >> 1, sbase = (tid & 1) << 6;
    float fdr[32], avs[32];
    #pragma unroll
    for (int c = 0; c < 8; ++c) {
        float4 v = *(const float4*)&FD[d][c * 4];
        fdr[c*4+0] = v.x; fdr[c*4+1] = v.y; fdr[c*4+2] = v.z; fdr[c*4+3] = v.w;
        float4 w = *(const float4*)&AVr[c * 4];
        avs[c*4+0] = 0.4f * w.x; avs[c*4+1] = 0.4f * w.y;
        avs[c*4+2] = 0.4f * w.z; avs[c*4+3] = 0.4f * w.w;
    }
    const float adc = Ad06[d];

    float Z = 0.f;
    float acc[32];
    #pragma unroll
    for (int o = 0; o < 32; ++o) acc[o] = 0.f;
    #pragma unroll 1
    for (int si = 0; si < 64; ++si) {
        const int s = sbase + si;
        float4 fa[8];
        #pragma unroll
        for (int c = 0; c < 8; ++c) fa[c] = *(const float4*)&FS[s][c * 4];
        float c0 = 0.f, c1 = 0.f, c2 = 0.f, c3 = 0.f;
        #pragma unroll
        for (int c = 0; c < 8; ++c) {
            float e0 = fdr[c*4+0] + fa[c].x; c0 = fmaf(avs[c*4+0], __builtin_fabsf(e0), c0);
            float e1 = fdr[c*4+1] + fa[c].y; c1 = fmaf(avs[c*4+1], __builtin_fabsf(e1), c1);
            float e2 = fdr[c*4+2] + fa[c].z; c2 = fmaf(avs[c*4+2], __builtin_fabsf(e2), c2);
            float e3 = fdr[c*4+3] + fa[c].w; c3 = fmaf(avs[c*4+3], __builtin_fabsf(e3), c3);
        }
        float v = adc + As06[s] + ((c0 + c1) + (c2 + c3));
        float e = (s == d) ? 0.f : __expf(v);
        Z += e;
        #pragma unroll
        for (int c = 0; c < 8; ++c) {
            acc[c*4+0] = fmaf(e, fa[c].x, acc[c*4+0]);
            acc[c*4+1] = fmaf(e, fa[c].y, acc[c*4+1]);
            acc[c*4+2] = fmaf(e, fa[c].z, acc[c*4+2]);
            acc[c*4+3] = fmaf(e, fa[c].w, acc[c*4+3]);
        }
    }
    Z += __shfl_xor(Z, 1);
    const float rz = fast_rcp(Z);
    #pragma unroll
    for (int o = 0; o < 32; ++o) acc[o] += __shfl_xor(acc[o], 1);

    float* dst = h1heads + ((size_t)((g * 8 + hd) * 128 + d)) * 32;
    const float* bp = b1 + hd * 32;
    if ((tid & 1) == 0) {
        #pragma unroll
        for (int c = 0; c < 4; ++c) {
            float4 v;
            v.x = fmaf(acc[c*4+0], rz, bp[c*4+0]);
            v.y = fmaf(acc[c*4+1], rz, bp[c*4+1]);
            v.z = fmaf(acc[c*4+2], rz, bp[c*4+2]);
            v.w = fmaf(acc[c*4+3], rz, bp[c*4+3]);
            *(float4*)(dst + c * 4) = v;
        }
    } else {
        #pragma unroll
        for (int c = 4; c < 8; ++c) {
            float4 v;
            v.x = fmaf(acc[c*4+0], rz, bp[c*4+0]);
            v.y = fmaf(acc[c*4+1], rz, bp[c*4+1]);
            v.z = fmaf(acc[c*4+2], rz, bp[c*4+2]);
            v.w = fmaf(acc[c*4+3], rz, bp[c*4+3]);
            *(float4*)(dst + c * 4) = v;
        }
    }
}

// ---------------------------------------------------------------------------
// GATv2 layer 2, single-pass, 256 threads (R5 config): one block per graph.
// ---------------------------------------------------------------------------
__global__ __launch_bounds__(256) void gat2_kernel(
    const float* __restrict__ h1heads, const float* __restrict__ W2s,
    const float* __restrict__ W2d, const float* __restrict__ a2,
    const float* __restrict__ b2, float* __restrict__ pooled)
{
    const int g = blockIdx.x;
    __shared__ float HS[128][36];
    __shared__ float FS[128][36];
    __shared__ float FD[128][36];     // reused as OUT after the fused pass
    __shared__ float AVr[32];
    __shared__ float As06[128];
    __shared__ float Ad06[128];
    const int tid = threadIdx.x;

    if (tid < 32) AVr[tid] = a2[tid];

    {
        #pragma unroll
        for (int i = 0; i < 4; ++i) {
            int idx4 = i * 256 + tid;
            float sx = 0.f, sy = 0.f, sz = 0.f, sw = 0.f;
            #pragma unroll
            for (int hdd = 0; hdd < 8; ++hdd) {
                const float4* src = (const float4*)(h1heads + (size_t)(g * 8 + hdd) * 4096);
                float4 v = src[idx4];
                sx += v.x; sy += v.y; sz += v.z; sw += v.w;
            }
            int n = idx4 >> 3, k0 = (idx4 & 7) * 4;
            float4 r; r.x = sx * 0.125f; r.y = sy * 0.125f; r.z = sz * 0.125f; r.w = sw * 0.125f;
            *(float4*)&HS[n][k0] = r;
        }
    }
    __syncthreads();

    {
        const int o = tid & 31, nb = tid >> 5;
        float wcs[32], wcd[32];
        const float* wsp = W2s + o;
        const float* wdp = W2d + o;
        #pragma unroll
        for (int k = 0; k < 32; ++k) { wcs[k] = wsp[k * 32]; wcd[k] = wdp[k * 32]; }
        #pragma unroll 1
        for (int n = nb * 16; n < nb * 16 + 16; ++n) {
            float a0 = 0.f, a1_ = 0.f, b0 = 0.f, b1_ = 0.f;
            #pragma unroll
            for (int k0 = 0; k0 < 32; k0 += 4) {
                const float4 hv = *(const float4*)&HS[n][k0];
                a0 = fmaf(hv.x, wcs[k0+0], a0); b0 = fmaf(hv.x, wcd[k0+0], b0);
                a1_ = fmaf(hv.y, wcs[k0+1], a1_); b1_ = fmaf(hv.y, wcd[k0+1], b1_);
                a0 = fmaf(hv.z, wcs[k0+2], a0); b0 = fmaf(hv.z, wcd[k0+2], b0);
                a1_ = fmaf(hv.w, wcs[k0+3], a1_); b1_ = fmaf(hv.w, wcd[k0+3], b1_);
            }
            FS[n][o] = a0 + a1_;
            FD[n][o] = b0 + b1_;
        }
    }
    __syncthreads();

    if (tid < 128) {
        float ss = 0.f, sd = 0.f;
        #pragma unroll
        for (int oo = 0; oo < 32; ++oo) {
            int o = (oo + tid) & 31;
            float a = AVr[o];
            ss = fmaf(a, FS[tid][o], ss);
            sd = fmaf(a, FD[tid][o], sd);
        }
        As06[tid] = 0.6f * ss;
        Ad06[tid] = 0.6f * sd;
    }
    __syncthreads();

    const int d = tid >> 1, sbase = (tid & 1) << 6;
    float fdr[32], avs[32];
    #pragma unroll
    for (int c = 0; c < 8; ++c) {
        float4 v = *(const float4*)&FD[d][c * 4];
        fdr[c*4+0] = v.x; fdr[c*4+1] = v.y; fdr[c*4+2] = v.z; fdr[c*4+3] = v.w;
        float4 w = *(const float4*)&AVr[c * 4];
        avs[c*4+0] = 0.4f * w.x; avs[c*4+1] = 0.4f * w.y;
        avs[c*4+2] = 0.4f * w.z; avs[c*4+3] = 0.4f * w.w;
    }
    const float adc = Ad06[d];

    float Z = 0.f;
    float acc[32];
    #pragma unroll
    for (int o = 0; o < 32; ++o) acc[o] = 0.f;
    #pragma unroll 1
    for (int si = 0; si < 64; ++si) {
        const int s = sbase + si;
        float4 fa[8];
        #pragma unroll
        for (int c = 0; c < 8; ++c) fa[c] = *(const float4*)&FS[s][c * 4];
        float c0 = 0.f, c1 = 0.f, c2 = 0.f, c3 = 0.f;
        #pragma unroll
        for (int c = 0; c < 8; ++c) {
            float e0 = fdr[c*4+0] + fa[c].x; c0 = fmaf(avs[c*4+0], __builtin_fabsf(e0), c0);
            float e1 = fdr[c*4+1] + fa[c].y; c1 = fmaf(avs[c*4+1], __builtin_fabsf(e1), c1);
            float e2 = fdr[c*4+2] + fa[c].z; c2 = fmaf(avs[c*4+2], __builtin_fabsf(e2), c2);
            float e3 = fdr[c*4+3] + fa[c].w; c3 = fmaf(avs[c*4+3], __builtin_fabsf(e3), c3);
        }
        float v = adc + As06[s] + ((c0 + c1) + (c2 + c3));
        float e = (s == d) ? 0.f : __expf(v);
        Z += e;
        #pragma unroll
        for (int c = 0; c < 8; ++c) {
            acc[c*4+0] = fmaf(e, fa[c].x, acc[c*4+0]);
            acc[c*4+1] = fmaf(e, fa[c].y, acc[c*4+1]);
            acc[c*4+2] = fmaf(e, fa[c].z, acc[c*4+2]);
            acc[c*4+3] = fmaf(e, fa[c].w, acc[c*4+3]);
        }
    }
    Z += __shfl_xor(Z, 1);
    const float rz = fast_rcp(Z);
    #pragma unroll
    for (int o = 0; o < 32; ++o) acc[o] += __shfl_xor(acc[o], 1);

    __syncthreads();
    if ((tid & 1) == 0) {
        #pragma unroll
        for (int c = 0; c < 4; ++c) {
            float4 v;
            v.x = acc[c*4+0] * rz; v.y = acc[c*4+1] * rz;
            v.z = acc[c*4+2] * rz; v.w = acc[c*4+3] * rz;
            *(float4*)&FD[d][c * 4] = v;
        }
    } else {
        #pragma unroll
        for (int c = 4; c < 8; ++c) {
            float4 v;
            v.x = acc[c*4+0] * rz; v.y = acc[c*4+1] * rz;
            v.z = acc[c*4+2] * rz; v.w = acc[c*4+3] * rz;
            *(float4*)&FD[d][c * 4] = v;
        }
    }
    __syncthreads();

    if (tid < 32) {
        float sp = 0.f;
        #pragma unroll 1
        for (int n = 0; n < 128; ++n) sp += FD[n][tid];
        pooled[g * 32 + tid] = fmaf(sp, 1.f / 128.f, b2[tid]);
    }
}

// ---------------------------------------------------------------------------
// Final: cosine sims, contrastive loss, output assembly.
// ---------------------------------------------------------------------------
__global__ void final_kernel(const float* __restrict__ pooled,
                             const float* __restrict__ hideout,
                             const float* __restrict__ timestep,
                             float* __restrict__ out)
{
    const int b = threadIdx.x;
    __shared__ float lossArr[16];
    if (b < 16) {
        const float* A  = pooled + b * 32;
        const float* Pv = pooled + (16 + b) * 32;
        float av[32];
        float na = 0.f;
        #pragma unroll
        for (int i = 0; i < 32; ++i) { av[i] = A[i]; na += av[i] * av[i]; }
        float npv = 0.f, dp = 0.f;
        #pragma unroll
        for (int i = 0; i < 32; ++i) { float p = Pv[i]; npv += p * p; dp += av[i] * p; }
        const float eps = 1e-6f;
        const float ia = 1.f / fmaxf(sqrtf(na), eps);
        const float sp = dp * ia / fmaxf(sqrtf(npv), eps);
        float sn[4];
        #pragma unroll
        for (int k = 0; k < 4; ++k) {
            const float* Nv = pooled + (32 + b * 4 + k) * 32;
            float nn = 0.f, dn = 0.f;
            #pragma unroll
            for (int i = 0; i < 32; ++i) { float q = Nv[i]; nn += q * q; dn += av[i] * q; }
            sn[k] = dn * ia / fmaxf(sqrtf(nn), eps);
        }
        float m = sp;
        #pragma unroll
        for (int k = 0; k < 4; ++k) m = fmaxf(m, sn[k]);
        float Z = expf(sp - m);
        #pragma unroll
        for (int k = 0; k < 4; ++k) Z += expf(sn[k] - m);
        lossArr[b] = logf(Z) + m - sp;
        float* r = out + b * 35;
        #pragma unroll
        for (int i = 0; i < 32; ++i) r[i] = av[i];
        r[32] = hideout[b * 2];
        r[33] = hideout[b * 2 + 1];
        r[34] = timestep[b];
    }
    __syncthreads();
    if (b == 0) {
        float s = 0.f;
        #pragma unroll
        for (int i = 0; i < 16; ++i) s += lossArr[i];
        out[560] = s * (1.f / 16.f);
    }
}

extern "C" void kernel_launch(void* const* d_in, const int* in_sizes, int n_in,
                              void* d_out, int out_size, void* d_ws, size_t ws_size,
                              hipStream_t stream) {
    const float* anchor   = (const float*)d_in[0];
    const float* pos      = (const float*)d_in[1];
    const float* neg      = (const float*)d_in[2];
    const float* hideout  = (const float*)d_in[3];
    const float* timestep = (const float*)d_in[4];
    const float* Wih      = (const float*)d_in[5];
    const float* Whh      = (const float*)d_in[6];
    const float* b_lstm   = (const float*)d_in[7];
    const float* W1s      = (const float*)d_in[8];
    const float* W1d      = (const float*)d_in[9];
    const float* a1       = (const float*)d_in[10];
    const float* b1       = (const float*)d_in[11];
    const float* W2s      = (const float*)d_in[12];
    const float* W2d      = (const float*)d_in[13];
    const float* a2       = (const float*)d_in[14];
    const float* b2       = (const float*)d_in[15];
    float* out = (float*)d_out;

    char* ws = (char*)d_ws;
    float* hn      = (float*)(ws);                       // 12288*32*4   = 1,572,864 B
    float* h1heads = (float*)(ws + 1605632);             // 96*8*128*32*4 = 12,582,912 B
    float* pooled  = (float*)(ws + 14188544);            // 96*32*4      = 12,288 B

    hipLaunchKernelGGL(lstm_mfma_kernel, dim3(192), dim3(256), 0, stream,
                       anchor, pos, neg, Wih, Whh, b_lstm, hn);
    hipLaunchKernelGGL(gat1_kernel,  dim3(768),  dim3(256), 0, stream,
                       hn, W1s, W1d, a1, b1, h1heads);
    hipLaunchKernelGGL(gat2_kernel,  dim3(96),   dim3(256), 0, stream,
                       h1heads, W2s, W2d, a2, b2, pooled);
    hipLaunchKernelGGL(final_kernel, dim3(1),    dim3(64),  0, stream,
                       pooled, hideout, timestep, out);
}